// Round 1
// baseline (9242.873 us; speedup 1.0000x reference)
//
#include <hip/hip_runtime.h>
#include <hip/hip_bf16.h>

// MLA forward, fp32 baseline.
// Shapes (fixed by setup_inputs): B=2, T=2048, C=2048, Lq=Lkv=512, nh=16, hs=128.
constexpr int Bc  = 2;
constexpr int Tc  = 2048;
constexpr int Cc  = 2048;
constexpr int LQ  = 512;
constexpr int LKV = 512;
constexpr int NHc = 16;
constexpr int HSc = 128;
constexpr int BT  = Bc * Tc;

// ---------------------------------------------------------------------------
// Generic strided fp32 GEMM: C[m,n] = sum_k A[m,k] * B[n,k]
// A[m,k] at A[m*lma + k*lka], B[n,k] at B[n*lmb + k*lkb].
// Requires M%64==0, N%64==0, K%16==0, and per operand either lk==1 (k-contig)
// or lm==1 (m-contig); strides multiples of 4 (float4 alignment).
// ---------------------------------------------------------------------------
__global__ __launch_bounds__(256)
void gemm_nt(const float* __restrict__ A, const float* __restrict__ B,
             float* __restrict__ C,
             int M, int N, int K, int lma, int lka, int lmb, int lkb)
{
  __shared__ float As[16][68];   // [k][m], pad 68 keeps f4 alignment + bank spread
  __shared__ float Bs[16][68];
  const int tid = threadIdx.x;
  const int bm = blockIdx.y * 64;
  const int bn = blockIdx.x * 64;
  const int tr = tid >> 4;   // 0..15
  const int tc = tid & 15;   // 0..15
  float acc[4][4] = {{0.f}};

  for (int k0 = 0; k0 < K; k0 += 16) {
    // --- stage A tile ---
    if (lka == 1) {
      const int m = tid >> 2, kf = (tid & 3) << 2;
      const float4 v = *(const float4*)(A + (size_t)(bm + m) * lma + (k0 + kf));
      As[kf + 0][m] = v.x; As[kf + 1][m] = v.y;
      As[kf + 2][m] = v.z; As[kf + 3][m] = v.w;
    } else {  // lma == 1
      const int k = tid >> 4, mf = (tid & 15) << 2;
      *(float4*)&As[k][mf] = *(const float4*)(A + (size_t)(k0 + k) * lka + (bm + mf));
    }
    // --- stage B tile ---
    if (lkb == 1) {
      const int n = tid >> 2, kf = (tid & 3) << 2;
      const float4 v = *(const float4*)(B + (size_t)(bn + n) * lmb + (k0 + kf));
      Bs[kf + 0][n] = v.x; Bs[kf + 1][n] = v.y;
      Bs[kf + 2][n] = v.z; Bs[kf + 3][n] = v.w;
    } else {  // lmb == 1
      const int k = tid >> 4, nf = (tid & 15) << 2;
      *(float4*)&Bs[k][nf] = *(const float4*)(B + (size_t)(k0 + k) * lkb + (bn + nf));
    }
    __syncthreads();
    #pragma unroll
    for (int k = 0; k < 16; ++k) {
      const float4 av = *(const float4*)&As[k][tr << 2];
      const float4 bv = *(const float4*)&Bs[k][tc << 2];
      const float ar[4] = {av.x, av.y, av.z, av.w};
      const float br[4] = {bv.x, bv.y, bv.z, bv.w};
      #pragma unroll
      for (int i = 0; i < 4; ++i)
        #pragma unroll
        for (int j = 0; j < 4; ++j)
          acc[i][j] += ar[i] * br[j];
    }
    __syncthreads();
  }
  #pragma unroll
  for (int i = 0; i < 4; ++i) {
    float4 v = {acc[i][0], acc[i][1], acc[i][2], acc[i][3]};
    *(float4*)(C + (size_t)(bm + (tr << 2) + i) * N + bn + (tc << 2)) = v;
  }
}

// ---------------------------------------------------------------------------
// Flash-style MLA attention, fp32.
// Block = (b, h, 32-row query tile), 256 threads = 32 rows x 8 lane-chunks.
// Each thread owns row r = tid>>3, 64 of the 512 latent columns (lane-chunk
// lc = tid&7). Column mapping for register index u (STATIC) -> physical f4
// unit cu = lc*16 + ((u+lc)&15): the +lc rotation spreads the 8 unique LDS
// addresses per instruction across 8x4 = 32 banks (rows broadcast for free).
// ---------------------------------------------------------------------------
__global__ __launch_bounds__(256)
void mla_attn(const float* __restrict__ qfull,  // (B*T, C)
              const float* __restrict__ Mk,     // (C, LKV)  = k_eff
              const float* __restrict__ ckv,    // (B*T, LKV)
              const float* __restrict__ Veff,   // (LKV, C)  = v_eff
              float* __restrict__ y)            // (B*T, C)
{
  __shared__ float ks[32][512];   // 64 KB: Mk chunk / K=V tile / ctx out
  __shared__ float qfs[32][33];   // q-head chunk (padded)
  __shared__ float ps[32][33];    // score tile (padded)

  const int b   = blockIdx.z;
  const int h   = blockIdx.y;
  const int tile = (int)(gridDim.x - 1) - (int)blockIdx.x;  // longest first
  const int t0  = tile << 5;
  const int tid = threadIdx.x;
  const int r   = tid >> 3;  // 0..31 query row within tile
  const int lc  = tid & 7;   // 0..7 column chunk

  // ---- stage 1: q_lat row (scaled) into registers ----
  float qreg[64];
  #pragma unroll
  for (int i = 0; i < 64; ++i) qreg[i] = 0.f;

  for (int d0 = 0; d0 < HSc; d0 += 32) {
    __syncthreads();
    {
      const float* src = Mk + (size_t)(h * HSc + d0) * LKV;
      #pragma unroll
      for (int e = 0; e < 16; ++e) {
        const int idx = tid + e * 256;            // 0..4095 f4 units
        const int row = idx >> 7, u = idx & 127;
        *(float4*)&ks[row][u << 2] =
            *(const float4*)&src[(size_t)row * LKV + (u << 2)];
      }
      #pragma unroll
      for (int e = 0; e < 4; ++e) {
        const int idx = tid + e * 256;
        const int row = idx >> 5, dd = idx & 31;
        qfs[row][dd] = qfull[(size_t)(b * Tc + t0 + row) * Cc + h * HSc + d0 + dd];
      }
    }
    __syncthreads();
    for (int dd = 0; dd < 32; ++dd) {
      const float qv = qfs[r][dd];
      #pragma unroll
      for (int u = 0; u < 16; ++u) {
        const int cu = (lc << 4) + ((u + lc) & 15);
        const float4 mv = *(const float4*)&ks[dd][cu << 2];
        qreg[4 * u + 0] += qv * mv.x;
        qreg[4 * u + 1] += qv * mv.y;
        qreg[4 * u + 2] += qv * mv.z;
        qreg[4 * u + 3] += qv * mv.w;
      }
    }
  }
  const float scale = 0.08838834764831845f;  // 1/sqrt(128)
  #pragma unroll
  for (int i = 0; i < 64; ++i) qreg[i] *= scale;

  // ---- stage 2: online-softmax flash loop over K/V tiles ----
  float cacc[64];
  #pragma unroll
  for (int i = 0; i < 64; ++i) cacc[i] = 0.f;
  float m_i = -__builtin_inff();
  float l_i = 0.f;

  const int ntile = tile + 1;
  for (int st = 0; st < ntile; ++st) {
    const int s0 = st << 5;
    __syncthreads();
    #pragma unroll
    for (int e = 0; e < 16; ++e) {
      const int idx = tid + e * 256;
      const int row = idx >> 7, u = idx & 127;
      *(float4*)&ks[row][u << 2] =
          *(const float4*)&ckv[(size_t)(b * Tc + s0 + row) * LKV + (u << 2)];
    }
    __syncthreads();

    // scores S[r][j] = q_lat[r] . K[j]  (partial per lane, width-8 reduce)
    const bool diag = (st == tile);
    for (int j = 0; j < 32; ++j) {
      float ax = 0.f, ay = 0.f, az = 0.f, aw = 0.f;
      #pragma unroll
      for (int u = 0; u < 16; ++u) {
        const int cu = (lc << 4) + ((u + lc) & 15);
        const float4 kv = *(const float4*)&ks[j][cu << 2];
        ax += qreg[4 * u + 0] * kv.x;
        ay += qreg[4 * u + 1] * kv.y;
        az += qreg[4 * u + 2] * kv.z;
        aw += qreg[4 * u + 3] * kv.w;
      }
      float s = (ax + ay) + (az + aw);
      s += __shfl_xor(s, 1);
      s += __shfl_xor(s, 2);
      s += __shfl_xor(s, 4);
      if (diag && j > r) s = -__builtin_inff();
      ps[r][j] = s;   // all 8 lanes write same value to same address (benign)
    }
    // row max (ps[r][*] produced by this wave's own lanes; same-wave LDS order ok)
    float tm = -__builtin_inff();
    for (int j = 0; j < 32; ++j) tm = fmaxf(tm, ps[r][j]);
    const float m_new = fmaxf(m_i, tm);
    const float sc = __expf(m_i - m_new);   // exp(-inf)=0 on first tile
    l_i *= sc;
    #pragma unroll
    for (int i = 0; i < 64; ++i) cacc[i] *= sc;

    for (int j = 0; j < 32; ++j) {
      const float p = __expf(ps[r][j] - m_new);
      l_i += p;
      #pragma unroll
      for (int u = 0; u < 16; ++u) {
        const int cu = (lc << 4) + ((u + lc) & 15);
        const float4 kv = *(const float4*)&ks[j][cu << 2];
        cacc[4 * u + 0] += p * kv.x;
        cacc[4 * u + 1] += p * kv.y;
        cacc[4 * u + 2] += p * kv.z;
        cacc[4 * u + 3] += p * kv.w;
      }
    }
    m_i = m_new;
  }

  // ---- epilogue: normalize ctx -> LDS, then y = ctx @ Veff_head ----
  __syncthreads();
  const float inv_l = 1.0f / l_i;
  #pragma unroll
  for (int u = 0; u < 16; ++u) {
    const int cu = (lc << 4) + ((u + lc) & 15);
    float4 v = {cacc[4 * u + 0] * inv_l, cacc[4 * u + 1] * inv_l,
                cacc[4 * u + 2] * inv_l, cacc[4 * u + 3] * inv_l};
    *(float4*)&ks[r][cu << 2] = v;
  }
  __syncthreads();

  const int rr = tid >> 3;
  const int dc = tid & 7;            // 8 chunks x 16 cols = 128 head dims
  float acc[16];
  #pragma unroll
  for (int e = 0; e < 16; ++e) acc[e] = 0.f;
  const float* vbase = Veff + h * HSc + (dc << 4);
  for (int l = 0; l < LKV; ++l) {
    const float cv = ks[rr][l];
    #pragma unroll
    for (int e4 = 0; e4 < 4; ++e4) {
      const float4 vv = *(const float4*)&vbase[(size_t)l * Cc + (e4 << 2)];
      acc[4 * e4 + 0] += cv * vv.x;
      acc[4 * e4 + 1] += cv * vv.y;
      acc[4 * e4 + 2] += cv * vv.z;
      acc[4 * e4 + 3] += cv * vv.w;
    }
  }
  float* yout = y + (size_t)(b * Tc + t0 + rr) * Cc + h * HSc + (dc << 4);
  #pragma unroll
  for (int e4 = 0; e4 < 4; ++e4) {
    float4 v = {acc[4 * e4 + 0], acc[4 * e4 + 1], acc[4 * e4 + 2], acc[4 * e4 + 3]};
    *(float4*)&yout[e4 << 2] = v;
  }
}

// ---------------------------------------------------------------------------
extern "C" void kernel_launch(void* const* d_in, const int* in_sizes, int n_in,
                              void* d_out, int out_size, void* d_ws, size_t ws_size,
                              hipStream_t stream)
{
  (void)in_sizes; (void)n_in; (void)out_size;

  const float* x    = (const float*)d_in[0];
  const float* Wdq  = (const float*)d_in[1];   // (LQ, C)
  const float* Wuq  = (const float*)d_in[2];   // (C, LQ)
  const float* Wdkv = (const float*)d_in[3];   // (LKV, C)
  const float* Wuk  = (const float*)d_in[4];   // (C, LKV)
  const float* Wuv  = (const float*)d_in[5];   // (C, LKV)
  const float* Wo   = (const float*)d_in[6];   // (C, C)

  float* y_out = (float*)d_out;                         // (B*T, C)
  float* ckv   = (float*)d_out + (size_t)BT * Cc;       // (B*T, LKV)

  // workspace layout (floats)
  float* ws    = (float*)d_ws;
  float* A1    = ws;                                    // LQ*LKV
  float* Mk    = A1 + (size_t)LQ * LKV;                 // C*LKV
  float* Veff  = Mk + (size_t)Cc * LKV;                 // LKV*C
  float* t1    = Veff + (size_t)LKV * Cc;               // BT*LQ
  float* qfull = t1 + (size_t)BT * LQ;                  // BT*C
  const size_t need = ((size_t)LQ * LKV + (size_t)Cc * LKV + (size_t)LKV * Cc +
                       (size_t)BT * LQ + (size_t)BT * Cc) * sizeof(float);
  if (ws_size < need) return;  // workspace too small -> loud validation failure

  const dim3 blk(256);

  // A1 = Wuq^T @ Wuk            (LQ, LKV), K=C
  gemm_nt<<<dim3(LKV / 64, LQ / 64), blk, 0, stream>>>(
      Wuq, Wuk, A1, LQ, LKV, Cc, 1, LQ, 1, LKV);
  // Mk = Wdq^T @ A1 = k_eff     (C, LKV), K=LQ
  gemm_nt<<<dim3(LKV / 64, Cc / 64), blk, 0, stream>>>(
      Wdq, A1, Mk, Cc, LKV, LQ, 1, Cc, 1, LKV);
  // Veff = Wuv^T @ Wo^T = v_eff (LKV, C), K=C
  gemm_nt<<<dim3(Cc / 64, LKV / 64), blk, 0, stream>>>(
      Wuv, Wo, Veff, LKV, Cc, Cc, 1, LKV, Cc, 1);
  // ckv = x @ Wdkv^T            (BT, LKV), K=C   -> second output
  gemm_nt<<<dim3(LKV / 64, BT / 64), blk, 0, stream>>>(
      x, Wdkv, ckv, BT, LKV, Cc, Cc, 1, Cc, 1);
  // t1 = x @ Wdq^T              (BT, LQ), K=C
  gemm_nt<<<dim3(LQ / 64, BT / 64), blk, 0, stream>>>(
      x, Wdq, t1, BT, LQ, Cc, Cc, 1, Cc, 1);
  // qfull = t1 @ Wuq^T          (BT, C), K=LQ
  gemm_nt<<<dim3(Cc / 64, BT / 64), blk, 0, stream>>>(
      t1, Wuq, qfull, BT, Cc, LQ, LQ, 1, LQ, 1);
  // flash attention + output projection (v_eff absorbed)
  mla_attn<<<dim3(Tc / 32, NHc, Bc), blk, 0, stream>>>(
      qfull, Mk, ckv, Veff, y_out);
}

// Round 2
// 2658.057 us; speedup vs baseline: 3.4773x; 3.4773x over previous
//
#include <hip/hip_runtime.h>
#include <hip/hip_bf16.h>

// MLA forward. Shapes fixed: B=2, T=2048, C=2048, Lq=Lkv=512, nh=16, hs=128.
constexpr int Bc  = 2;
constexpr int Tc  = 2048;
constexpr int Cc  = 2048;
constexpr int LQ  = 512;
constexpr int LKV = 512;
constexpr int HSc = 128;
constexpr int BT  = Bc * Tc;

typedef __attribute__((ext_vector_type(8))) short bf16x8;
typedef __attribute__((ext_vector_type(4))) float f32x4;

union FragU { unsigned int u[4]; bf16x8 v; uint4 q; };

static __device__ __forceinline__ unsigned int pk_bf16(float lo, float hi) {
  unsigned int r;
  asm volatile("v_cvt_pk_bf16_f32 %0, %1, %2" : "=v"(r) : "v"(lo), "v"(hi));
  return r;
}

// ---------------------------------------------------------------------------
// Generic strided fp32 GEMM: C[m,n] = sum_k A[m,k]*B[n,k]; optional bf16 out.
// ---------------------------------------------------------------------------
template <int BF16OUT>
__global__ __launch_bounds__(256)
void gemm_nt(const float* __restrict__ A, const float* __restrict__ B,
             void* __restrict__ Cout,
             int M, int N, int K, int lma, int lka, int lmb, int lkb)
{
  __shared__ float As[16][68];
  __shared__ float Bs[16][68];
  const int tid = threadIdx.x;
  const int bm = blockIdx.y * 64;
  const int bn = blockIdx.x * 64;
  const int tr = tid >> 4;
  const int tc = tid & 15;
  float acc[4][4] = {{0.f}};

  for (int k0 = 0; k0 < K; k0 += 16) {
    if (lka == 1) {
      const int m = tid >> 2, kf = (tid & 3) << 2;
      const float4 v = *(const float4*)(A + (size_t)(bm + m) * lma + (k0 + kf));
      As[kf + 0][m] = v.x; As[kf + 1][m] = v.y;
      As[kf + 2][m] = v.z; As[kf + 3][m] = v.w;
    } else {
      const int k = tid >> 4, mf = (tid & 15) << 2;
      *(float4*)&As[k][mf] = *(const float4*)(A + (size_t)(k0 + k) * lka + (bm + mf));
    }
    if (lkb == 1) {
      const int n = tid >> 2, kf = (tid & 3) << 2;
      const float4 v = *(const float4*)(B + (size_t)(bn + n) * lmb + (k0 + kf));
      Bs[kf + 0][n] = v.x; Bs[kf + 1][n] = v.y;
      Bs[kf + 2][n] = v.z; Bs[kf + 3][n] = v.w;
    } else {
      const int k = tid >> 4, nf = (tid & 15) << 2;
      *(float4*)&Bs[k][nf] = *(const float4*)(B + (size_t)(k0 + k) * lkb + (bn + nf));
    }
    __syncthreads();
    #pragma unroll
    for (int k = 0; k < 16; ++k) {
      const float4 av = *(const float4*)&As[k][tr << 2];
      const float4 bv = *(const float4*)&Bs[k][tc << 2];
      const float ar[4] = {av.x, av.y, av.z, av.w};
      const float br[4] = {bv.x, bv.y, bv.z, bv.w};
      #pragma unroll
      for (int i = 0; i < 4; ++i)
        #pragma unroll
        for (int j = 0; j < 4; ++j)
          acc[i][j] += ar[i] * br[j];
    }
    __syncthreads();
  }
  if (BF16OUT) {
    unsigned short* Cb = (unsigned short*)Cout;
    #pragma unroll
    for (int i = 0; i < 4; ++i) {
      uint2 o;
      o.x = pk_bf16(acc[i][0], acc[i][1]);
      o.y = pk_bf16(acc[i][2], acc[i][3]);
      *(uint2*)(Cb + (size_t)(bm + (tr << 2) + i) * N + bn + (tc << 2)) = o;
    }
  } else {
    float* Cf = (float*)Cout;
    #pragma unroll
    for (int i = 0; i < 4; ++i) {
      float4 v = {acc[i][0], acc[i][1], acc[i][2], acc[i][3]};
      *(float4*)(Cf + (size_t)(bm + (tr << 2) + i) * N + bn + (tc << 2)) = v;
    }
  }
}

// ---------------------------------------------------------------------------
// ckv f32 -> bf16 cast (row-major copy)
// ---------------------------------------------------------------------------
__global__ __launch_bounds__(256)
void cast_f32_bf16(const float* __restrict__ src, unsigned short* __restrict__ dst,
                   int n4)
{
  const int idx = blockIdx.x * 256 + threadIdx.x;
  for (int i = idx; i < n4; i += gridDim.x * 256) {
    const float4 v = *(const float4*)(src + (size_t)i * 4);
    uint2 o;
    o.x = pk_bf16(v.x, v.y);
    o.y = pk_bf16(v.z, v.w);
    *(uint2*)(dst + (size_t)i * 4) = o;
  }
}

// ---------------------------------------------------------------------------
// ckv (B*T x 512 f32) -> ckvT_b [b][512][T] bf16
// ---------------------------------------------------------------------------
__global__ __launch_bounds__(256)
void transpose_ckv(const float* __restrict__ ckv, unsigned short* __restrict__ ckvT)
{
  __shared__ float tile[32][33];
  const int tb = blockIdx.x;   // T/32
  const int lb = blockIdx.y;   // 512/32
  const int b  = blockIdx.z;
  const int tid = threadIdx.x;
  const int r  = tid >> 3;
  const int c4 = (tid & 7) << 2;
  const float4 v = *(const float4*)(ckv + (size_t)(b * Tc + tb * 32 + r) * LKV + lb * 32 + c4);
  tile[r][c4 + 0] = v.x; tile[r][c4 + 1] = v.y;
  tile[r][c4 + 2] = v.z; tile[r][c4 + 3] = v.w;
  __syncthreads();
  uint2 o;
  o.x = pk_bf16(tile[c4 + 0][r], tile[c4 + 1][r]);
  o.y = pk_bf16(tile[c4 + 2][r], tile[c4 + 3][r]);
  *(uint2*)(ckvT + (size_t)(b * LKV + lb * 32 + r) * Tc + tb * 32 + c4) = o;
}

// ---------------------------------------------------------------------------
// MFMA flash attention (transposed orientation).
// Block = (64-q tile, head, batch); 256 thr = 4 waves; wave w owns q [16w,16w+16).
// S^T = K.Q_lat^T ; ctx^T = V^T.P^T ; y^T = v_eff^T.ctx^T.
// LDS: K row-major [32][512] bf16 (16B-XOR swizzle), Vt [512][32] bf16 (8B-XOR).
// Q / P / ctx stay in registers; P,ctx B-fragments built via cvt_pk + shfl.
// ---------------------------------------------------------------------------
__global__ __launch_bounds__(256, 2)
void mla_attn_mfma(const unsigned short* __restrict__ qfull_b,  // (BT, C)
                   const unsigned short* __restrict__ MkT_b,    // (512, C)  k_eff^T
                   const unsigned short* __restrict__ ckv_b,    // (BT, 512)
                   const unsigned short* __restrict__ ckvT_b,   // [b][512][T]
                   const unsigned short* __restrict__ VeffT_b,  // (C, 512)  v_eff^T
                   float* __restrict__ y)                       // (BT, C)
{
  __shared__ unsigned short Kl[32 * 512];   // 32 KB
  __shared__ unsigned short Vt[512 * 32];   // 32 KB

  const int tid  = threadIdx.x;
  const int lane = tid & 63;
  const int w    = tid >> 6;
  const int g    = lane >> 4;
  const int l15  = lane & 15;
  const int b    = blockIdx.z;
  const int h    = blockIdx.y;
  const int t0   = blockIdx.x * 64;
  const int qw   = t0 + 16 * w;       // wave q base
  const int qg   = qw + l15;          // lane's query row (global)

  const f32x4 zero4 = {0.f, 0.f, 0.f, 0.f};
  f32x4 acc[32];
  #pragma unroll
  for (int i = 0; i < 32; ++i) acc[i] = zero4;

  // ---- prologue: q_lat^T = MkT . qfull^T  (acc[lf]: lat frag lf, col=q) ----
  #pragma unroll
  for (int ks4 = 0; ks4 < 4; ++ks4) {
    const bf16x8 bq = *(const bf16x8*)(qfull_b + (size_t)(b * Tc + qw + l15) * Cc
                                      + h * HSc + ks4 * 32 + g * 8);
    #pragma unroll
    for (int lf = 0; lf < 32; ++lf) {
      const bf16x8 aq = *(const bf16x8*)(MkT_b + (size_t)(16 * lf + l15) * Cc
                                         + h * HSc + ks4 * 32 + g * 8);
      acc[lf] = __builtin_amdgcn_mfma_f32_16x16x32_bf16(aq, bq, acc[lf], 0, 0, 0);
    }
  }
  const float scale = 0.08838834764831845f;  // 1/sqrt(128)
  #pragma unroll
  for (int i = 0; i < 32; ++i) {
    acc[i][0] *= scale; acc[i][1] *= scale; acc[i][2] *= scale; acc[i][3] *= scale;
  }

  // ---- pack Q into B-fragments (col=q, k=lat), via cvt_pk + shfl ----
  const int srcA = ((2 * (g & 1)) << 4) | l15;
  const int srcB = srcA + 16;
  const bool hiF = (g >> 1);
  bf16x8 qb[16];
  #pragma unroll
  for (int ks = 0; ks < 16; ++ks) {
    const unsigned int w00 = pk_bf16(acc[2 * ks][0], acc[2 * ks][1]);
    const unsigned int w01 = pk_bf16(acc[2 * ks][2], acc[2 * ks][3]);
    const unsigned int w10 = pk_bf16(acc[2 * ks + 1][0], acc[2 * ks + 1][1]);
    const unsigned int w11 = pk_bf16(acc[2 * ks + 1][2], acc[2 * ks + 1][3]);
    FragU f;
    unsigned int a, c;
    a = __shfl((int)w00, srcA); c = __shfl((int)w10, srcA); f.u[0] = hiF ? c : a;
    a = __shfl((int)w01, srcA); c = __shfl((int)w11, srcA); f.u[1] = hiF ? c : a;
    a = __shfl((int)w00, srcB); c = __shfl((int)w10, srcB); f.u[2] = hiF ? c : a;
    a = __shfl((int)w01, srcB); c = __shfl((int)w11, srcB); f.u[3] = hiF ? c : a;
    qb[ks] = f.v;
  }
  #pragma unroll
  for (int i = 0; i < 32; ++i) acc[i] = zero4;   // acc becomes ctx^T

  float m_i = -__builtin_inff();
  float l_i = 0.f;

  // ---- main flash loop over 32-key tiles ----
  const int ntiles = (t0 >> 5) + 2;
  for (int st = 0; st < ntiles; ++st) {
    const int s0 = st * 32;
    __syncthreads();
    // stage K rows (pre-swizzled source, linear dest; read XOR = 16B-unit ^ (key&7))
    #pragma unroll
    for (int e = 0; e < 8; ++e) {
      const int idx = tid + 256 * e;         // 16B units
      const int row = idx >> 6, u = idx & 63;
      const uint4 kv = *(const uint4*)(ckv_b + (size_t)(b * Tc + s0 + row) * LKV
                                       + ((u ^ (row & 7)) * 8));
      *(uint4*)((char*)Kl + idx * 16) = kv;
    }
    // stage Vt rows (8B units, read XOR = 8B-unit ^ (lat&7))
    #pragma unroll
    for (int e = 0; e < 16; ++e) {
      const int idx = tid + 256 * e;         // 8B units
      const int lat = idx >> 3, u = idx & 7;
      const uint2 vv = *(const uint2*)(ckvT_b + (size_t)(b * LKV + lat) * Tc
                                       + s0 + ((u ^ (lat & 7)) * 4));
      *(uint2*)((char*)Vt + idx * 8) = vv;
    }
    __syncthreads();

    if (s0 > qw + 15) continue;   // fully masked for this wave (barriers done)

    // --- QK: S^T strips (2 key-frags x 16 k-steps) ---
    f32x4 s0f = zero4, s1f = zero4;
    #pragma unroll
    for (int ks = 0; ks < 16; ++ks) {
      const int sw = (l15 & 7) << 4;
      const bf16x8 a0 = *(const bf16x8*)((char*)Kl + (l15) * 1024
                                         + ((ks * 64 + g * 16) ^ sw));
      const bf16x8 a1 = *(const bf16x8*)((char*)Kl + (16 + l15) * 1024
                                         + ((ks * 64 + g * 16) ^ sw));
      s0f = __builtin_amdgcn_mfma_f32_16x16x32_bf16(a0, qb[ks], s0f, 0, 0, 0);
      s1f = __builtin_amdgcn_mfma_f32_16x16x32_bf16(a1, qb[ks], s1f, 0, 0, 0);
    }

    // --- mask + online softmax (per-lane stats; q = col = lane&15) ---
    float sv[8];
    #pragma unroll
    for (int r = 0; r < 4; ++r) { sv[r] = s0f[r]; sv[4 + r] = s1f[r]; }
    if (s0 + 31 > qw) {   // diagonal-ish tile: apply causal mask
      #pragma unroll
      for (int kf = 0; kf < 2; ++kf)
        #pragma unroll
        for (int r = 0; r < 4; ++r) {
          const int key = s0 + 16 * kf + 4 * g + r;
          if (key > qg) sv[4 * kf + r] = -__builtin_inff();
        }
    }
    float vmax = sv[0];
    #pragma unroll
    for (int i = 1; i < 8; ++i) vmax = fmaxf(vmax, sv[i]);
    vmax = fmaxf(vmax, __shfl_xor(vmax, 16));
    vmax = fmaxf(vmax, __shfl_xor(vmax, 32));

    if (!__all(vmax <= m_i + 8.0f)) {       // defer-max: rescale only on growth
      const float m_new = fmaxf(m_i, vmax);
      const float scl = __expf(m_i - m_new);
      l_i *= scl;
      #pragma unroll
      for (int i = 0; i < 32; ++i) {
        acc[i][0] *= scl; acc[i][1] *= scl; acc[i][2] *= scl; acc[i][3] *= scl;
      }
      m_i = m_new;
    }

    float p[8];
    float lsum = 0.f;
    #pragma unroll
    for (int i = 0; i < 8; ++i) { p[i] = __expf(sv[i] - m_i); lsum += p[i]; }
    lsum += __shfl_xor(lsum, 16);
    lsum += __shfl_xor(lsum, 32);
    l_i += lsum;

    // --- build P^T B-fragment (col=q, k=key 0..31) ---
    const unsigned int W00 = pk_bf16(p[0], p[1]);
    const unsigned int W01 = pk_bf16(p[2], p[3]);
    const unsigned int W10 = pk_bf16(p[4], p[5]);
    const unsigned int W11 = pk_bf16(p[6], p[7]);
    FragU pf;
    {
      unsigned int a, c;
      a = __shfl((int)W00, srcA); c = __shfl((int)W10, srcA); pf.u[0] = hiF ? c : a;
      a = __shfl((int)W01, srcA); c = __shfl((int)W11, srcA); pf.u[1] = hiF ? c : a;
      a = __shfl((int)W00, srcB); c = __shfl((int)W10, srcB); pf.u[2] = hiF ? c : a;
      a = __shfl((int)W01, srcB); c = __shfl((int)W11, srcB); pf.u[3] = hiF ? c : a;
    }

    // --- PV: ctx^T += V^T . P^T ---
    const int swv = (l15 & 7) << 3;
    #pragma unroll
    for (int lf = 0; lf < 32; ++lf) {
      const char* vp = (char*)Vt + (16 * lf + l15) * 64;
      const uint2 lo = *(const uint2*)(vp + ((g * 16) ^ swv));
      const uint2 hi = *(const uint2*)(vp + ((g * 16 + 8) ^ swv));
      FragU av;
      av.u[0] = lo.x; av.u[1] = lo.y; av.u[2] = hi.x; av.u[3] = hi.y;
      acc[lf] = __builtin_amdgcn_mfma_f32_16x16x32_bf16(av.v, pf.v, acc[lf], 0, 0, 0);
    }
  }

  // ---- epilogue: y^T = v_eff^T . (ctx^T / l) ----
  const float inv_l = 1.0f / l_i;
  f32x4 yacc[8];
  #pragma unroll
  for (int i = 0; i < 8; ++i) yacc[i] = zero4;

  #pragma unroll
  for (int ks = 0; ks < 16; ++ks) {
    const unsigned int w00 = pk_bf16(acc[2 * ks][0] * inv_l, acc[2 * ks][1] * inv_l);
    const unsigned int w01 = pk_bf16(acc[2 * ks][2] * inv_l, acc[2 * ks][3] * inv_l);
    const unsigned int w10 = pk_bf16(acc[2 * ks + 1][0] * inv_l, acc[2 * ks + 1][1] * inv_l);
    const unsigned int w11 = pk_bf16(acc[2 * ks + 1][2] * inv_l, acc[2 * ks + 1][3] * inv_l);
    FragU cf;
    unsigned int a, c;
    a = __shfl((int)w00, srcA); c = __shfl((int)w10, srcA); cf.u[0] = hiF ? c : a;
    a = __shfl((int)w01, srcA); c = __shfl((int)w11, srcA); cf.u[1] = hiF ? c : a;
    a = __shfl((int)w00, srcB); c = __shfl((int)w10, srcB); cf.u[2] = hiF ? c : a;
    a = __shfl((int)w01, srcB); c = __shfl((int)w11, srcB); cf.u[3] = hiF ? c : a;
    #pragma unroll
    for (int hf = 0; hf < 8; ++hf) {
      const bf16x8 aV = *(const bf16x8*)(VeffT_b + (size_t)(h * HSc + 16 * hf + l15) * LKV
                                         + ks * 32 + g * 8);
      yacc[hf] = __builtin_amdgcn_mfma_f32_16x16x32_bf16(aV, cf.v, yacc[hf], 0, 0, 0);
    }
  }
  #pragma unroll
  for (int hf = 0; hf < 8; ++hf)
    #pragma unroll
    for (int r = 0; r < 4; ++r) {
      const int d = 16 * hf + 4 * g + r;
      y[(size_t)(b * Tc + qg) * Cc + h * HSc + d] = yacc[hf][r];
    }
}

// ---------------------------------------------------------------------------
extern "C" void kernel_launch(void* const* d_in, const int* in_sizes, int n_in,
                              void* d_out, int out_size, void* d_ws, size_t ws_size,
                              hipStream_t stream)
{
  (void)in_sizes; (void)n_in; (void)out_size;

  const float* x    = (const float*)d_in[0];
  const float* Wdq  = (const float*)d_in[1];   // (LQ, C)
  const float* Wuq  = (const float*)d_in[2];   // (C, LQ)
  const float* Wdkv = (const float*)d_in[3];   // (LKV, C)
  const float* Wuk  = (const float*)d_in[4];   // (C, LKV)
  const float* Wuv  = (const float*)d_in[5];   // (C, LKV)
  const float* Wo   = (const float*)d_in[6];   // (C, C)

  float* y_out = (float*)d_out;                         // (BT, C)
  float* ckv   = (float*)d_out + (size_t)BT * Cc;       // (BT, LKV) fp32 (output)

  constexpr size_t MB = 1ull << 20;
  char* ws = (char*)d_ws;
  float*          A1      = (float*)(ws + 0);            // 512x512 f32   (1 MB)
  float*          t1      = (float*)(ws + 1 * MB);       // 4096x512 f32  (8 MB)
  unsigned short* MkT_b   = (unsigned short*)(ws + 9 * MB);   // 512x2048  (2 MB)
  unsigned short* VeffT_b = (unsigned short*)(ws + 11 * MB);  // 2048x512  (2 MB)
  unsigned short* qfull_b = (unsigned short*)(ws + 13 * MB);  // 4096x2048 (16 MB)
  unsigned short* ckv_b   = (unsigned short*)(ws + 29 * MB);  // 4096x512  (4 MB)
  unsigned short* ckvT_b  = (unsigned short*)(ws + 33 * MB);  // 2x512x2048 (4 MB)
  if (ws_size < 37 * MB) return;  // loud failure if workspace too small

  const dim3 blk(256);

  // A1 = Wuq^T @ Wuk                 (512, 512), K=C
  gemm_nt<0><<<dim3(LKV / 64, LQ / 64), blk, 0, stream>>>(
      Wuq, Wuk, A1, LQ, LKV, Cc, 1, LQ, 1, LKV);
  // MkT_b = (A1^T @ Wdq) = k_eff^T   (512, C), K=LQ  [bf16]
  gemm_nt<1><<<dim3(Cc / 64, LKV / 64), blk, 0, stream>>>(
      A1, Wdq, MkT_b, LKV, Cc, LQ, 1, LKV, 1, Cc);
  // VeffT_b = (Wo @ Wuv) = v_eff^T   (C, 512), K=C  [bf16]
  gemm_nt<1><<<dim3(LKV / 64, Cc / 64), blk, 0, stream>>>(
      Wo, Wuv, VeffT_b, Cc, LKV, Cc, Cc, 1, 1, LKV);
  // ckv = x @ Wdkv^T                 (BT, 512), K=C  [f32 -> output]
  gemm_nt<0><<<dim3(LKV / 64, BT / 64), blk, 0, stream>>>(
      x, Wdkv, ckv, BT, LKV, Cc, Cc, 1, Cc, 1);
  // t1 = x @ Wdq^T                   (BT, LQ), K=C
  gemm_nt<0><<<dim3(LQ / 64, BT / 64), blk, 0, stream>>>(
      x, Wdq, t1, BT, LQ, Cc, Cc, 1, Cc, 1);
  // qfull_b = t1 @ Wuq^T             (BT, C), K=LQ  [bf16]
  gemm_nt<1><<<dim3(Cc / 64, BT / 64), blk, 0, stream>>>(
      t1, Wuq, qfull_b, BT, Cc, LQ, LQ, 1, LQ, 1);
  // bf16 copies of ckv (row-major + transposed)
  cast_f32_bf16<<<dim3(1024), blk, 0, stream>>>(ckv, ckv_b, BT * LKV / 4);
  transpose_ckv<<<dim3(Tc / 32, LKV / 32, Bc), blk, 0, stream>>>(ckv, ckvT_b);
  // flash attention + absorbed output projection
  mla_attn_mfma<<<dim3(Tc / 64, 16, Bc), blk, 0, stream>>>(
      qfull_b, MkT_b, ckv_b, ckvT_b, VeffT_b, y_out);
}

// Round 6
// 1609.020 us; speedup vs baseline: 5.7444x; 1.6520x over previous
//
#include <hip/hip_runtime.h>
#include <hip/hip_bf16.h>

// MLA forward. Shapes fixed: B=2, T=2048, C=2048, Lq=Lkv=512, nh=16, hs=128.
constexpr int Bc  = 2;
constexpr int Tc  = 2048;
constexpr int Cc  = 2048;
constexpr int LQ  = 512;
constexpr int LKV = 512;
constexpr int HSc = 128;
constexpr int BT  = Bc * Tc;

typedef __attribute__((ext_vector_type(8))) short bf16x8;
typedef __attribute__((ext_vector_type(4))) float f32x4;

union FragU { unsigned int u[4]; bf16x8 v; uint4 q; };

static __device__ __forceinline__ unsigned int pk_bf16(float lo, float hi) {
  unsigned int r;
  asm volatile("v_cvt_pk_bf16_f32 %0, %1, %2" : "=v"(r) : "v"(lo), "v"(hi));
  return r;
}

// Build a 16x16x32 B-fragment (col = q, k-slots) from per-lane packed pairs.
// Copied verbatim from the round-2 validated kernel.
static __device__ __forceinline__ bf16x8 pack_frag(
    unsigned int w00, unsigned int w01, unsigned int w10, unsigned int w11,
    int srcA, int srcB, bool hiF)
{
  FragU f;
  unsigned int a, c;
  a = __shfl((int)w00, srcA); c = __shfl((int)w10, srcA); f.u[0] = hiF ? c : a;
  a = __shfl((int)w01, srcA); c = __shfl((int)w11, srcA); f.u[1] = hiF ? c : a;
  a = __shfl((int)w00, srcB); c = __shfl((int)w10, srcB); f.u[2] = hiF ? c : a;
  a = __shfl((int)w01, srcB); c = __shfl((int)w11, srcB); f.u[3] = hiF ? c : a;
  return f.v;
}

// ---------------------------------------------------------------------------
// Generic strided fp32 GEMM (kept for small A1 / MkT): C[m,n]=sum_k A[m,k]B[n,k]
// ---------------------------------------------------------------------------
template <int BF16OUT>
__global__ __launch_bounds__(256)
void gemm_nt(const float* __restrict__ A, const float* __restrict__ B,
             void* __restrict__ Cout,
             int M, int N, int K, int lma, int lka, int lmb, int lkb)
{
  __shared__ float As[16][68];
  __shared__ float Bs[16][68];
  const int tid = threadIdx.x;
  const int bm = blockIdx.y * 64;
  const int bn = blockIdx.x * 64;
  const int tr = tid >> 4;
  const int tc = tid & 15;
  float acc[4][4] = {{0.f}};

  for (int k0 = 0; k0 < K; k0 += 16) {
    if (lka == 1) {
      const int m = tid >> 2, kf = (tid & 3) << 2;
      const float4 v = *(const float4*)(A + (size_t)(bm + m) * lma + (k0 + kf));
      As[kf + 0][m] = v.x; As[kf + 1][m] = v.y;
      As[kf + 2][m] = v.z; As[kf + 3][m] = v.w;
    } else {
      const int k = tid >> 4, mf = (tid & 15) << 2;
      *(float4*)&As[k][mf] = *(const float4*)(A + (size_t)(k0 + k) * lka + (bm + mf));
    }
    if (lkb == 1) {
      const int n = tid >> 2, kf = (tid & 3) << 2;
      const float4 v = *(const float4*)(B + (size_t)(bn + n) * lmb + (k0 + kf));
      Bs[kf + 0][n] = v.x; Bs[kf + 1][n] = v.y;
      Bs[kf + 2][n] = v.z; Bs[kf + 3][n] = v.w;
    } else {
      const int k = tid >> 4, nf = (tid & 15) << 2;
      *(float4*)&Bs[k][nf] = *(const float4*)(B + (size_t)(k0 + k) * lkb + (bn + nf));
    }
    __syncthreads();
    #pragma unroll
    for (int k = 0; k < 16; ++k) {
      const float4 av = *(const float4*)&As[k][tr << 2];
      const float4 bv = *(const float4*)&Bs[k][tc << 2];
      const float ar[4] = {av.x, av.y, av.z, av.w};
      const float br[4] = {bv.x, bv.y, bv.z, bv.w};
      #pragma unroll
      for (int i = 0; i < 4; ++i)
        #pragma unroll
        for (int j = 0; j < 4; ++j)
          acc[i][j] += ar[i] * br[j];
    }
    __syncthreads();
  }
  if (BF16OUT) {
    unsigned short* Cb = (unsigned short*)Cout;
    #pragma unroll
    for (int i = 0; i < 4; ++i) {
      uint2 o;
      o.x = pk_bf16(acc[i][0], acc[i][1]);
      o.y = pk_bf16(acc[i][2], acc[i][3]);
      *(uint2*)(Cb + (size_t)(bm + (tr << 2) + i) * N + bn + (tc << 2)) = o;
    }
  } else {
    float* Cf = (float*)Cout;
    #pragma unroll
    for (int i = 0; i < 4; ++i) {
      float4 v = {acc[i][0], acc[i][1], acc[i][2], acc[i][3]};
      *(float4*)(Cf + (size_t)(bm + (tr << 2) + i) * N + bn + (tc << 2)) = v;
    }
  }
}

// ---------------------------------------------------------------------------
// bf16 MFMA GEMM: C[m,n] = sum_k A[m,k]*B[n,k], k-contiguous operands.
// SPLIT=1: Dekker split (hi/lo planes, 3 MFMA terms) -> fp32-grade accuracy.
// M%128==0, N%128==0, K%64==0. 256 thr / 4 waves, 128x128 tile, dbuf LDS.
// ---------------------------------------------------------------------------
template <int SPLIT, int F32OUT>
__global__ __launch_bounds__(256, 2)
void gemm_bt_bf16(const unsigned short* __restrict__ Ah,
                  const unsigned short* __restrict__ Al,
                  const unsigned short* __restrict__ Bh,
                  const unsigned short* __restrict__ Bl,
                  void* __restrict__ Cout, int M, int N, int K)
{
  constexpr int BK  = SPLIT ? 32 : 64;     // k per tile
  constexpr int BKu = BK / 8;              // 16B units per row (4 or 8)
  constexpr int NU  = 128 * BKu / 256;     // units per thread per plane (2 or 4)
  constexpr int KS  = SPLIT ? 1 : 2;       // 32-wide MFMA k-steps per tile
  __shared__ unsigned short As[2][SPLIT + 1][128 * BK];
  __shared__ unsigned short Bs[2][SPLIT + 1][128 * BK];

  const int tid  = threadIdx.x;
  const int lane = tid & 63;
  const int wv   = tid >> 6;
  const int g    = lane >> 4;
  const int l15  = lane & 15;
  const int wm   = wv >> 1, wn = wv & 1;
  const int bm   = blockIdx.y * 128, bn = blockIdx.x * 128;

  const f32x4 zero4 = {0.f, 0.f, 0.f, 0.f};
  f32x4 acc[4][4];
  #pragma unroll
  for (int i = 0; i < 4; ++i)
    #pragma unroll
    for (int j = 0; j < 4; ++j) acc[i][j] = zero4;

  uint4 rah[NU], rbh[NU], ral[NU], rbl[NU];

  // ---- stage tile 0 into regs ----
  #pragma unroll
  for (int e = 0; e < NU; ++e) {
    const int idx = tid + 256 * e;
    const int r = idx / BKu;
    const int u = (idx & (BKu - 1)) ^ (SPLIT ? ((r ^ (r >> 2)) & 3) : (r & 7));
    rah[e] = *(const uint4*)(Ah + (size_t)(bm + r) * K + u * 8);
    rbh[e] = *(const uint4*)(Bh + (size_t)(bn + r) * K + u * 8);
    if constexpr (SPLIT) {
      ral[e] = *(const uint4*)(Al + (size_t)(bm + r) * K + u * 8);
      rbl[e] = *(const uint4*)(Bl + (size_t)(bn + r) * K + u * 8);
    }
  }
  #pragma unroll
  for (int e = 0; e < NU; ++e) {
    const int idx = tid + 256 * e;
    *(uint4*)((char*)&As[0][0][0] + idx * 16) = rah[e];
    *(uint4*)((char*)&Bs[0][0][0] + idx * 16) = rbh[e];
    if constexpr (SPLIT) {
      *(uint4*)((char*)&As[0][1][0] + idx * 16) = ral[e];
      *(uint4*)((char*)&Bs[0][1][0] + idx * 16) = rbl[e];
    }
  }
  __syncthreads();

  const int nk = K / BK;
  for (int t = 0; t < nk; ++t) {
    const int buf = t & 1;
    const bool hn = (t + 1 < nk);
    if (hn) {
      const int k0 = (t + 1) * BK;
      #pragma unroll
      for (int e = 0; e < NU; ++e) {
        const int idx = tid + 256 * e;
        const int r = idx / BKu;
        const int u = (idx & (BKu - 1)) ^ (SPLIT ? ((r ^ (r >> 2)) & 3) : (r & 7));
        rah[e] = *(const uint4*)(Ah + (size_t)(bm + r) * K + k0 + u * 8);
        rbh[e] = *(const uint4*)(Bh + (size_t)(bn + r) * K + k0 + u * 8);
        if constexpr (SPLIT) {
          ral[e] = *(const uint4*)(Al + (size_t)(bm + r) * K + k0 + u * 8);
          rbl[e] = *(const uint4*)(Bl + (size_t)(bn + r) * K + k0 + u * 8);
        }
      }
    }
    #pragma unroll
    for (int ks = 0; ks < KS; ++ks) {
      bf16x8 fah[4], fbh[4], fal[4], fbl[4];
      #pragma unroll
      for (int i = 0; i < 4; ++i) {
        const int ar = wm * 64 + i * 16 + l15;
        const int br = wn * 64 + i * 16 + l15;
        const int ua = (ks * 4 + g) ^ (SPLIT ? ((ar ^ (ar >> 2)) & 3) : (ar & 7));
        const int ub = (ks * 4 + g) ^ (SPLIT ? ((br ^ (br >> 2)) & 3) : (br & 7));
        fah[i] = *(const bf16x8*)((const char*)&As[buf][0][0] + ar * (BK * 2) + ua * 16);
        fbh[i] = *(const bf16x8*)((const char*)&Bs[buf][0][0] + br * (BK * 2) + ub * 16);
        if constexpr (SPLIT) {
          fal[i] = *(const bf16x8*)((const char*)&As[buf][1][0] + ar * (BK * 2) + ua * 16);
          fbl[i] = *(const bf16x8*)((const char*)&Bs[buf][1][0] + br * (BK * 2) + ub * 16);
        }
      }
      #pragma unroll
      for (int i = 0; i < 4; ++i)
        #pragma unroll
        for (int j = 0; j < 4; ++j) {
          acc[i][j] = __builtin_amdgcn_mfma_f32_16x16x32_bf16(fah[i], fbh[j], acc[i][j], 0, 0, 0);
          if constexpr (SPLIT) {
            acc[i][j] = __builtin_amdgcn_mfma_f32_16x16x32_bf16(fah[i], fbl[j], acc[i][j], 0, 0, 0);
            acc[i][j] = __builtin_amdgcn_mfma_f32_16x16x32_bf16(fal[i], fbh[j], acc[i][j], 0, 0, 0);
          }
        }
      if (ks == 0 && hn) {   // write prefetched tile to the other buffer
        #pragma unroll
        for (int e = 0; e < NU; ++e) {
          const int idx = tid + 256 * e;
          *(uint4*)((char*)&As[buf ^ 1][0][0] + idx * 16) = rah[e];
          *(uint4*)((char*)&Bs[buf ^ 1][0][0] + idx * 16) = rbh[e];
          if constexpr (SPLIT) {
            *(uint4*)((char*)&As[buf ^ 1][1][0] + idx * 16) = ral[e];
            *(uint4*)((char*)&Bs[buf ^ 1][1][0] + idx * 16) = rbl[e];
          }
        }
      }
    }
    __syncthreads();
  }

  // epilogue: D col = lane&15 (n), row = 4g + r (m)
  #pragma unroll
  for (int i = 0; i < 4; ++i) {
    const int m = bm + wm * 64 + i * 16 + 4 * g;
    #pragma unroll
    for (int j = 0; j < 4; ++j) {
      const int n = bn + wn * 64 + j * 16 + l15;
      #pragma unroll
      for (int r = 0; r < 4; ++r) {
        const float v = acc[i][j][r];
        if constexpr (F32OUT)
          ((float*)Cout)[(size_t)(m + r) * N + n] = v;
        else
          ((unsigned short*)Cout)[(size_t)(m + r) * N + n] =
              (unsigned short)(pk_bf16(v, v) & 0xffffu);
      }
    }
  }
}

// ---------------------------------------------------------------------------
// f32 -> bf16 cast
// ---------------------------------------------------------------------------
__global__ __launch_bounds__(256)
void cast_f32_bf16(const float* __restrict__ src, unsigned short* __restrict__ dst,
                   int n4)
{
  const int idx = blockIdx.x * 256 + threadIdx.x;
  for (int i = idx; i < n4; i += gridDim.x * 256) {
    const float4 v = *(const float4*)(src + (size_t)i * 4);
    uint2 o;
    o.x = pk_bf16(v.x, v.y);
    o.y = pk_bf16(v.z, v.w);
    *(uint2*)(dst + (size_t)i * 4) = o;
  }
}

// ---------------------------------------------------------------------------
// f32 -> Dekker split (hi = rne_bf16(x), lo = rne_bf16(x - hi))
// ---------------------------------------------------------------------------
__global__ __launch_bounds__(256)
void split_cast(const float* __restrict__ src, unsigned short* __restrict__ hi,
                unsigned short* __restrict__ lo, int n4)
{
  const int idx = blockIdx.x * 256 + threadIdx.x;
  for (int i = idx; i < n4; i += gridDim.x * 256) {
    const float4 v = *(const float4*)(src + (size_t)i * 4);
    const unsigned int h0 = pk_bf16(v.x, v.y);
    const unsigned int h1 = pk_bf16(v.z, v.w);
    const float ax = __uint_as_float((h0 & 0xffffu) << 16);
    const float ay = __uint_as_float(h0 & 0xffff0000u);
    const float az = __uint_as_float((h1 & 0xffffu) << 16);
    const float aw = __uint_as_float(h1 & 0xffff0000u);
    const unsigned int l0 = pk_bf16(v.x - ax, v.y - ay);
    const unsigned int l1 = pk_bf16(v.z - az, v.w - aw);
    uint2 oh = {h0, h1}, ol = {l0, l1};
    *(uint2*)(hi + (size_t)i * 4) = oh;
    *(uint2*)(lo + (size_t)i * 4) = ol;
  }
}

// ---------------------------------------------------------------------------
// transpose + bf16 cast: src (z, R, C) f32 -> dst (z, C, R) bf16
// ---------------------------------------------------------------------------
__global__ __launch_bounds__(256)
void transpose_cast(const float* __restrict__ src, unsigned short* __restrict__ dst,
                    int R, int C)
{
  __shared__ float tile[32][33];
  const int rb = blockIdx.x * 32, cb = blockIdx.y * 32, z = blockIdx.z;
  const float* s = src + (size_t)z * R * C;
  unsigned short* d = dst + (size_t)z * R * C;
  const int r  = threadIdx.x >> 3;
  const int c4 = (threadIdx.x & 7) << 2;
  const float4 v = *(const float4*)(s + (size_t)(rb + r) * C + cb + c4);
  tile[r][c4 + 0] = v.x; tile[r][c4 + 1] = v.y;
  tile[r][c4 + 2] = v.z; tile[r][c4 + 3] = v.w;
  __syncthreads();
  uint2 o;
  o.x = pk_bf16(tile[c4 + 0][r], tile[c4 + 1][r]);
  o.y = pk_bf16(tile[c4 + 2][r], tile[c4 + 3][r]);
  *(uint2*)(d + (size_t)(cb + r) * R + rb + c4) = o;
}

// ---------------------------------------------------------------------------
// MFMA flash attention v2: head-shared K/V staging.
// Block = 512 thr = 8 waves; wave w = head hg*8+w; all waves share one
// 16-query tile. Pair scheduling (tiles i and 127-i) equalizes causal work:
// 256 blocks == 1 per CU. K tile [32][512] bf16 (16B-XOR swz), Vt [512][32]
// (16B-XOR swz), double-buffered, 1 barrier/tile, loads prefetched to regs
// before QK and written to the idle buffer after softmax.
// ---------------------------------------------------------------------------
static __device__ __forceinline__ void stage_load(
    const unsigned short* __restrict__ ckv_b,
    const unsigned short* __restrict__ ckvT_b,
    int b, int s0, int tid, uint4* rk, uint4* rv)
{
  #pragma unroll
  for (int e = 0; e < 4; ++e) {
    const int idx = tid + 512 * e;
    const int row = idx >> 6;
    const int u   = (idx & 63) ^ (row & 7);
    rk[e] = *(const uint4*)(ckv_b + (size_t)(b * Tc + s0 + row) * LKV + u * 8);
    const int lat = idx >> 2;
    const int uv  = (idx & 3) ^ ((lat ^ (lat >> 2)) & 3);
    rv[e] = *(const uint4*)(ckvT_b + (size_t)(b * LKV + lat) * Tc + s0 + uv * 8);
  }
}

__global__ __launch_bounds__(512, 2)
void mla_attn_mfma2(const unsigned short* __restrict__ qfull_b,  // (BT, C)
                    const unsigned short* __restrict__ MkT_b,    // (512, C)
                    const unsigned short* __restrict__ ckv_b,    // (BT, 512)
                    const unsigned short* __restrict__ ckvT_b,   // [b][512][T]
                    const unsigned short* __restrict__ VeffT_b,  // (C, 512)
                    float* __restrict__ y)                       // (BT, C)
{
  __shared__ unsigned short Kl[2][32 * 512];   // 2 x 32 KB
  __shared__ unsigned short Vt[2][512 * 32];   // 2 x 32 KB

  const int tid  = threadIdx.x;
  const int lane = tid & 63;
  const int w    = tid >> 6;
  const int g    = lane >> 4;
  const int l15  = lane & 15;

  // XCD-aware decode: each XCD sticks to one (batch, head-group)
  const int bid   = blockIdx.x;
  const int xcd   = bid & 7;
  const int slot  = bid >> 3;
  const int b     = xcd >> 2;
  const int hg    = (xcd >> 1) & 1;
  const int ipair = (slot << 1) | (xcd & 1);   // 0..63
  const int h     = hg * 8 + w;

  const int srcA = ((2 * (g & 1)) << 4) | l15;
  const int srcB = srcA + 16;
  const bool hiF = (g >> 1);
  const f32x4 zero4 = {0.f, 0.f, 0.f, 0.f};

  for (int half = 0; half < 2; ++half) {
    const int qt = half ? (127 - ipair) : ipair;
    const int q0 = qt << 4;
    const int qg = q0 + l15;

    // ---- issue tile-0 staging loads early (hidden under q_lat prologue) ----
    uint4 rk[4], rv[4];
    stage_load(ckv_b, ckvT_b, b, 0, tid, rk, rv);

    // ---- prologue: q_lat^T = MkT . qfull^T (per-head) ----
    f32x4 acc[32];
    #pragma unroll
    for (int i = 0; i < 32; ++i) acc[i] = zero4;
    #pragma unroll
    for (int ks4 = 0; ks4 < 4; ++ks4) {
      const bf16x8 bq = *(const bf16x8*)(qfull_b + (size_t)(b * Tc + q0 + l15) * Cc
                                         + h * HSc + ks4 * 32 + g * 8);
      #pragma unroll
      for (int lf = 0; lf < 32; ++lf) {
        const bf16x8 aq = *(const bf16x8*)(MkT_b + (size_t)(16 * lf + l15) * Cc
                                           + h * HSc + ks4 * 32 + g * 8);
        acc[lf] = __builtin_amdgcn_mfma_f32_16x16x32_bf16(aq, bq, acc[lf], 0, 0, 0);
      }
    }
    const float scale = 0.08838834764831845f;  // 1/sqrt(128)
    #pragma unroll
    for (int i = 0; i < 32; ++i) {
      acc[i][0] *= scale; acc[i][1] *= scale; acc[i][2] *= scale; acc[i][3] *= scale;
    }

    // ---- pack Q into B-fragments ----
    bf16x8 qb[16];
    #pragma unroll
    for (int ks = 0; ks < 16; ++ks) {
      const unsigned int w00 = pk_bf16(acc[2 * ks][0], acc[2 * ks][1]);
      const unsigned int w01 = pk_bf16(acc[2 * ks][2], acc[2 * ks][3]);
      const unsigned int w10 = pk_bf16(acc[2 * ks + 1][0], acc[2 * ks + 1][1]);
      const unsigned int w11 = pk_bf16(acc[2 * ks + 1][2], acc[2 * ks + 1][3]);
      qb[ks] = pack_frag(w00, w01, w10, w11, srcA, srcB, hiF);
    }
    #pragma unroll
    for (int i = 0; i < 32; ++i) acc[i] = zero4;   // acc becomes ctx^T

    // ---- write tile 0 to buffer 0 ----
    #pragma unroll
    for (int e = 0; e < 4; ++e) {
      const int idx = tid + 512 * e;
      *(uint4*)((char*)&Kl[0][0] + idx * 16) = rk[e];
      *(uint4*)((char*)&Vt[0][0] + idx * 16) = rv[e];
    }
    float m_i = -__builtin_inff();
    float l_i = 0.f;
    __syncthreads();

    const int ntiles = ((q0 + 15) >> 5) + 1;
    for (int st = 0; st < ntiles; ++st) {
      const int cur = st & 1;
      const int s0  = st * 32;
      const bool hasNext = (st + 1 < ntiles);
      if (hasNext) stage_load(ckv_b, ckvT_b, b, s0 + 32, tid, rk, rv);

      // --- QK: S^T strips ---
      f32x4 s0f = zero4, s1f = zero4;
      #pragma unroll
      for (int ks = 0; ks < 16; ++ks) {
        const int off = ((ks * 4 + g) ^ (l15 & 7)) * 16;
        const bf16x8 a0 = *(const bf16x8*)((const char*)&Kl[cur][0] + l15 * 1024 + off);
        const bf16x8 a1 = *(const bf16x8*)((const char*)&Kl[cur][0] + (16 + l15) * 1024 + off);
        s0f = __builtin_amdgcn_mfma_f32_16x16x32_bf16(a0, qb[ks], s0f, 0, 0, 0);
        s1f = __builtin_amdgcn_mfma_f32_16x16x32_bf16(a1, qb[ks], s1f, 0, 0, 0);
      }

      // --- mask + online softmax (per-lane stats; q = col = lane&15) ---
      float sv[8];
      #pragma unroll
      for (int r = 0; r < 4; ++r) { sv[r] = s0f[r]; sv[4 + r] = s1f[r]; }
      if (st == ntiles - 1) {
        #pragma unroll
        for (int kf = 0; kf < 2; ++kf)
          #pragma unroll
          for (int r = 0; r < 4; ++r) {
            const int key = s0 + 16 * kf + 4 * g + r;
            if (key > qg) sv[4 * kf + r] = -__builtin_inff();
          }
      }
      float vmax = sv[0];
      #pragma unroll
      for (int i = 1; i < 8; ++i) vmax = fmaxf(vmax, sv[i]);
      vmax = fmaxf(vmax, __shfl_xor(vmax, 16));
      vmax = fmaxf(vmax, __shfl_xor(vmax, 32));

      if (!__all(vmax <= m_i + 8.0f)) {   // defer-max
        const float m_new = fmaxf(m_i, vmax);
        const float scl = __expf(m_i - m_new);
        l_i *= scl;
        #pragma unroll
        for (int i = 0; i < 32; ++i) {
          acc[i][0] *= scl; acc[i][1] *= scl; acc[i][2] *= scl; acc[i][3] *= scl;
        }
        m_i = m_new;
      }

      float p[8];
      float lsum = 0.f;
      #pragma unroll
      for (int i = 0; i < 8; ++i) { p[i] = __expf(sv[i] - m_i); lsum += p[i]; }
      lsum += __shfl_xor(lsum, 16);
      lsum += __shfl_xor(lsum, 32);
      l_i += lsum;

      // --- write prefetched tile into the idle buffer (T14 async-split) ---
      if (hasNext) {
        #pragma unroll
        for (int e = 0; e < 4; ++e) {
          const int idx = tid + 512 * e;
          *(uint4*)((char*)&Kl[cur ^ 1][0] + idx * 16) = rk[e];
          *(uint4*)((char*)&Vt[cur ^ 1][0] + idx * 16) = rv[e];
        }
      }

      // --- build P^T B-fragment ---
      const unsigned int W00 = pk_bf16(p[0], p[1]);
      const unsigned int W01 = pk_bf16(p[2], p[3]);
      const unsigned int W10 = pk_bf16(p[4], p[5]);
      const unsigned int W11 = pk_bf16(p[6], p[7]);
      const bf16x8 pfr = pack_frag(W00, W01, W10, W11, srcA, srcB, hiF);

      // --- PV: ctx^T += V^T . P^T ---
      #pragma unroll
      for (int lf = 0; lf < 32; ++lf) {
        const int lat = 16 * lf + l15;
        const bf16x8 av = *(const bf16x8*)((const char*)&Vt[cur][0] + lat * 64
                                           + ((g ^ ((lat ^ (lat >> 2)) & 3)) * 16));
        acc[lf] = __builtin_amdgcn_mfma_f32_16x16x32_bf16(av, pfr, acc[lf], 0, 0, 0);
      }
      __syncthreads();
    }

    // ---- epilogue: y^T = v_eff^T . (ctx^T / l) ----
    const float inv_l = 1.0f / l_i;
    f32x4 yacc[8];
    #pragma unroll
    for (int i = 0; i < 8; ++i) yacc[i] = zero4;
    #pragma unroll
    for (int ks = 0; ks < 16; ++ks) {
      const unsigned int w00 = pk_bf16(acc[2 * ks][0] * inv_l, acc[2 * ks][1] * inv_l);
      const unsigned int w01 = pk_bf16(acc[2 * ks][2] * inv_l, acc[2 * ks][3] * inv_l);
      const unsigned int w10 = pk_bf16(acc[2 * ks + 1][0] * inv_l, acc[2 * ks + 1][1] * inv_l);
      const unsigned int w11 = pk_bf16(acc[2 * ks + 1][2] * inv_l, acc[2 * ks + 1][3] * inv_l);
      const bf16x8 cf = pack_frag(w00, w01, w10, w11, srcA, srcB, hiF);
      #pragma unroll
      for (int hf = 0; hf < 8; ++hf) {
        const bf16x8 aV = *(const bf16x8*)(VeffT_b + (size_t)(h * HSc + 16 * hf + l15) * LKV
                                           + ks * 32 + g * 8);
        yacc[hf] = __builtin_amdgcn_mfma_f32_16x16x32_bf16(aV, cf, yacc[hf], 0, 0, 0);
      }
    }
    float* yp = y + (size_t)(b * Tc + qg) * Cc + h * HSc;
    #pragma unroll
    for (int hf = 0; hf < 8; ++hf) {
      float4 v = {yacc[hf][0], yacc[hf][1], yacc[hf][2], yacc[hf][3]};
      *(float4*)(yp + 16 * hf + 4 * g) = v;
    }
  }
}

// ---------------------------------------------------------------------------
extern "C" void kernel_launch(void* const* d_in, const int* in_sizes, int n_in,
                              void* d_out, int out_size, void* d_ws, size_t ws_size,
                              hipStream_t stream)
{
  (void)in_sizes; (void)n_in; (void)out_size;

  const float* x    = (const float*)d_in[0];
  const float* Wdq  = (const float*)d_in[1];   // (LQ, C)
  const float* Wuq  = (const float*)d_in[2];   // (C, LQ)
  const float* Wdkv = (const float*)d_in[3];   // (LKV, C)
  const float* Wuk  = (const float*)d_in[4];   // (C, LKV)
  const float* Wuv  = (const float*)d_in[5];   // (C, LKV)
  const float* Wo   = (const float*)d_in[6];   // (C, C)

  float* y_out = (float*)d_out;                         // (BT, C)
  float* ckv   = (float*)d_out + (size_t)BT * Cc;       // (BT, LKV) fp32 output

  constexpr size_t MB = 1ull << 20;
  char* ws = (char*)d_ws;
  if (ws_size < 48 * MB) return;  // loud failure if workspace too small

  // phase-1 layout
  unsigned short* xh    = (unsigned short*)(ws + 0 * MB);    // 16MB
  unsigned short* xl    = (unsigned short*)(ws + 16 * MB);   // 16MB
  unsigned short* Wdqh  = (unsigned short*)(ws + 32 * MB);   // 2MB
  unsigned short* Wdql  = (unsigned short*)(ws + 34 * MB);   // 2MB
  float*          t1f   = (float*)         (ws + 36 * MB);   // 8MB
  unsigned short* Wdkvh = (unsigned short*)(ws + 44 * MB);   // 2MB
  unsigned short* Wdkvl = (unsigned short*)(ws + 46 * MB);   // 2MB  (peak 48MB)
  // phase-2 layout (reuses freed regions)
  unsigned short* t1h     = (unsigned short*)(ws + 0 * MB);  // 4MB
  unsigned short* t1l     = (unsigned short*)(ws + 4 * MB);  // 4MB
  unsigned short* Wuqh    = (unsigned short*)(ws + 8 * MB);  // 2MB
  unsigned short* Wuql    = (unsigned short*)(ws + 10 * MB); // 2MB
  unsigned short* qfull_b = (unsigned short*)(ws + 12 * MB); // 16MB -> 28
  unsigned short* ckvT_b  = (unsigned short*)(ws + 28 * MB); // 4MB  -> 32
  unsigned short* ckv_b   = (unsigned short*)(ws + 32 * MB); // 4MB  -> 36
  unsigned short* MkT_b   = (unsigned short*)(ws + 36 * MB); // 2MB  -> 38
  float*          A1      = (float*)         (ws + 44 * MB); // 1MB
  unsigned short* Wo_b    = (unsigned short*)(ws + 0 * MB);  // 8MB (after t1 dead)
  unsigned short* WuvT_b  = (unsigned short*)(ws + 8 * MB);  // 2MB (after Wuq dead)
  unsigned short* VeffT_b = (unsigned short*)(ws + 10 * MB); // 2MB

  const dim3 blk(256);

  // q/kv projection path (Dekker split -> fp32-grade MFMA)
  split_cast<<<2048, blk, 0, stream>>>(x, xh, xl, BT * Cc / 4);
  split_cast<<<512, blk, 0, stream>>>(Wdq, Wdqh, Wdql, LQ * Cc / 4);
  gemm_bt_bf16<1, 1><<<dim3(LQ / 128, BT / 128), blk, 0, stream>>>(
      xh, xl, Wdqh, Wdql, t1f, BT, LQ, Cc);
  split_cast<<<512, blk, 0, stream>>>(Wdkv, Wdkvh, Wdkvl, LKV * Cc / 4);
  gemm_bt_bf16<1, 1><<<dim3(LKV / 128, BT / 128), blk, 0, stream>>>(
      xh, xl, Wdkvh, Wdkvl, ckv, BT, LKV, Cc);                 // ckv output
  split_cast<<<512, blk, 0, stream>>>(t1f, t1h, t1l, BT * LQ / 4);
  split_cast<<<512, blk, 0, stream>>>(Wuq, Wuqh, Wuql, Cc * LQ / 4);
  gemm_bt_bf16<1, 0><<<dim3(Cc / 128, BT / 128), blk, 0, stream>>>(
      t1h, t1l, Wuqh, Wuql, qfull_b, BT, Cc, LQ);
  // v_eff^T = Wo @ Wuv (plain bf16 MFMA)
  cast_f32_bf16<<<1024, blk, 0, stream>>>(Wo, Wo_b, Cc * Cc / 4);
  transpose_cast<<<dim3(Cc / 32, LKV / 32, 1), blk, 0, stream>>>(Wuv, WuvT_b, Cc, LKV);
  gemm_bt_bf16<0, 0><<<dim3(LKV / 128, Cc / 128), blk, 0, stream>>>(
      Wo_b, nullptr, WuvT_b, nullptr, VeffT_b, Cc, LKV, Cc);
  // k_eff^T (small, fp32 vector path, identical to validated round 2)
  gemm_nt<0><<<dim3(LKV / 64, LQ / 64), blk, 0, stream>>>(
      Wuq, Wuk, A1, LQ, LKV, Cc, 1, LQ, 1, LKV);
  gemm_nt<1><<<dim3(Cc / 64, LKV / 64), blk, 0, stream>>>(
      A1, Wdq, MkT_b, LKV, Cc, LQ, 1, LKV, 1, Cc);
  // bf16 copies of ckv
  cast_f32_bf16<<<1024, blk, 0, stream>>>(ckv, ckv_b, BT * LKV / 4);
  transpose_cast<<<dim3(Tc / 32, LKV / 32, Bc), blk, 0, stream>>>(ckv, ckvT_b, Tc, LKV);
  // flash attention + absorbed output projection
  mla_attn_mfma2<<<dim3(256), dim3(512), 0, stream>>>(
      qfull_b, MkT_b, ckv_b, ckvT_b, VeffT_b, y_out);
}

// Round 7
// 1571.008 us; speedup vs baseline: 5.8834x; 1.0242x over previous
//
#include <hip/hip_runtime.h>
#include <hip/hip_bf16.h>

// MLA forward. Shapes fixed: B=2, T=2048, C=2048, Lq=Lkv=512, nh=16, hs=128.
constexpr int Bc  = 2;
constexpr int Tc  = 2048;
constexpr int Cc  = 2048;
constexpr int LQ  = 512;
constexpr int LKV = 512;
constexpr int HSc = 128;
constexpr int BT  = Bc * Tc;

typedef __attribute__((ext_vector_type(8))) short bf16x8;
typedef __attribute__((ext_vector_type(4))) float f32x4;

union FragU { unsigned int u[4]; bf16x8 v; uint4 q; };

static __device__ __forceinline__ unsigned int pk_bf16(float lo, float hi) {
  unsigned int r;
  asm volatile("v_cvt_pk_bf16_f32 %0, %1, %2" : "=v"(r) : "v"(lo), "v"(hi));
  return r;
}

// Build a 16x16x32 B-fragment (col = q, k-slots) from per-lane packed pairs.
static __device__ __forceinline__ bf16x8 pack_frag(
    unsigned int w00, unsigned int w01, unsigned int w10, unsigned int w11,
    int srcA, int srcB, bool hiF)
{
  FragU f;
  unsigned int a, c;
  a = __shfl((int)w00, srcA); c = __shfl((int)w10, srcA); f.u[0] = hiF ? c : a;
  a = __shfl((int)w01, srcA); c = __shfl((int)w11, srcA); f.u[1] = hiF ? c : a;
  a = __shfl((int)w00, srcB); c = __shfl((int)w10, srcB); f.u[2] = hiF ? c : a;
  a = __shfl((int)w01, srcB); c = __shfl((int)w11, srcB); f.u[3] = hiF ? c : a;
  return f.v;
}

// ---------------------------------------------------------------------------
// Generic strided fp32 GEMM (kept for small A1 / MkT): C[m,n]=sum_k A[m,k]B[n,k]
// ---------------------------------------------------------------------------
template <int BF16OUT>
__global__ __launch_bounds__(256)
void gemm_nt(const float* __restrict__ A, const float* __restrict__ B,
             void* __restrict__ Cout,
             int M, int N, int K, int lma, int lka, int lmb, int lkb)
{
  __shared__ float As[16][68];
  __shared__ float Bs[16][68];
  const int tid = threadIdx.x;
  const int bm = blockIdx.y * 64;
  const int bn = blockIdx.x * 64;
  const int tr = tid >> 4;
  const int tc = tid & 15;
  float acc[4][4] = {{0.f}};

  for (int k0 = 0; k0 < K; k0 += 16) {
    if (lka == 1) {
      const int m = tid >> 2, kf = (tid & 3) << 2;
      const float4 v = *(const float4*)(A + (size_t)(bm + m) * lma + (k0 + kf));
      As[kf + 0][m] = v.x; As[kf + 1][m] = v.y;
      As[kf + 2][m] = v.z; As[kf + 3][m] = v.w;
    } else {
      const int k = tid >> 4, mf = (tid & 15) << 2;
      *(float4*)&As[k][mf] = *(const float4*)(A + (size_t)(k0 + k) * lka + (bm + mf));
    }
    if (lkb == 1) {
      const int n = tid >> 2, kf = (tid & 3) << 2;
      const float4 v = *(const float4*)(B + (size_t)(bn + n) * lmb + (k0 + kf));
      Bs[kf + 0][n] = v.x; Bs[kf + 1][n] = v.y;
      Bs[kf + 2][n] = v.z; Bs[kf + 3][n] = v.w;
    } else {
      const int k = tid >> 4, nf = (tid & 15) << 2;
      *(float4*)&Bs[k][nf] = *(const float4*)(B + (size_t)(k0 + k) * lkb + (bn + nf));
    }
    __syncthreads();
    #pragma unroll
    for (int k = 0; k < 16; ++k) {
      const float4 av = *(const float4*)&As[k][tr << 2];
      const float4 bv = *(const float4*)&Bs[k][tc << 2];
      const float ar[4] = {av.x, av.y, av.z, av.w};
      const float br[4] = {bv.x, bv.y, bv.z, bv.w};
      #pragma unroll
      for (int i = 0; i < 4; ++i)
        #pragma unroll
        for (int j = 0; j < 4; ++j)
          acc[i][j] += ar[i] * br[j];
    }
    __syncthreads();
  }
  if (BF16OUT) {
    unsigned short* Cb = (unsigned short*)Cout;
    #pragma unroll
    for (int i = 0; i < 4; ++i) {
      uint2 o;
      o.x = pk_bf16(acc[i][0], acc[i][1]);
      o.y = pk_bf16(acc[i][2], acc[i][3]);
      *(uint2*)(Cb + (size_t)(bm + (tr << 2) + i) * N + bn + (tc << 2)) = o;
    }
  } else {
    float* Cf = (float*)Cout;
    #pragma unroll
    for (int i = 0; i < 4; ++i) {
      float4 v = {acc[i][0], acc[i][1], acc[i][2], acc[i][3]};
      *(float4*)(Cf + (size_t)(bm + (tr << 2) + i) * N + bn + (tc << 2)) = v;
    }
  }
}

// ---------------------------------------------------------------------------
// bf16 MFMA GEMM: C[m,n] = sum_k A[m,k]*B[n,k], k-contiguous operands.
// SPLIT=1: Dekker split (hi/lo planes, 3 MFMA terms) -> fp32-grade accuracy.
// M%128==0, N%128==0, K%64==0. 256 thr / 4 waves, 128x128 tile, dbuf LDS.
// ---------------------------------------------------------------------------
template <int SPLIT, int F32OUT>
__global__ __launch_bounds__(256, 2)
void gemm_bt_bf16(const unsigned short* __restrict__ Ah,
                  const unsigned short* __restrict__ Al,
                  const unsigned short* __restrict__ Bh,
                  const unsigned short* __restrict__ Bl,
                  void* __restrict__ Cout, int M, int N, int K)
{
  constexpr int BK  = SPLIT ? 32 : 64;     // k per tile
  constexpr int BKu = BK / 8;              // 16B units per row (4 or 8)
  constexpr int NU  = 128 * BKu / 256;     // units per thread per plane (2 or 4)
  constexpr int KS  = SPLIT ? 1 : 2;       // 32-wide MFMA k-steps per tile
  __shared__ unsigned short As[2][SPLIT + 1][128 * BK];
  __shared__ unsigned short Bs[2][SPLIT + 1][128 * BK];

  const int tid  = threadIdx.x;
  const int lane = tid & 63;
  const int wv   = tid >> 6;
  const int g    = lane >> 4;
  const int l15  = lane & 15;
  const int wm   = wv >> 1, wn = wv & 1;
  const int bm   = blockIdx.y * 128, bn = blockIdx.x * 128;

  const f32x4 zero4 = {0.f, 0.f, 0.f, 0.f};
  f32x4 acc[4][4];
  #pragma unroll
  for (int i = 0; i < 4; ++i)
    #pragma unroll
    for (int j = 0; j < 4; ++j) acc[i][j] = zero4;

  uint4 rah[NU], rbh[NU], ral[NU], rbl[NU];

  // ---- stage tile 0 into regs ----
  #pragma unroll
  for (int e = 0; e < NU; ++e) {
    const int idx = tid + 256 * e;
    const int r = idx / BKu;
    const int u = (idx & (BKu - 1)) ^ (SPLIT ? ((r ^ (r >> 2)) & 3) : (r & 7));
    rah[e] = *(const uint4*)(Ah + (size_t)(bm + r) * K + u * 8);
    rbh[e] = *(const uint4*)(Bh + (size_t)(bn + r) * K + u * 8);
    if constexpr (SPLIT) {
      ral[e] = *(const uint4*)(Al + (size_t)(bm + r) * K + u * 8);
      rbl[e] = *(const uint4*)(Bl + (size_t)(bn + r) * K + u * 8);
    }
  }
  #pragma unroll
  for (int e = 0; e < NU; ++e) {
    const int idx = tid + 256 * e;
    *(uint4*)((char*)&As[0][0][0] + idx * 16) = rah[e];
    *(uint4*)((char*)&Bs[0][0][0] + idx * 16) = rbh[e];
    if constexpr (SPLIT) {
      *(uint4*)((char*)&As[0][1][0] + idx * 16) = ral[e];
      *(uint4*)((char*)&Bs[0][1][0] + idx * 16) = rbl[e];
    }
  }
  __syncthreads();

  const int nk = K / BK;
  for (int t = 0; t < nk; ++t) {
    const int buf = t & 1;
    const bool hn = (t + 1 < nk);
    if (hn) {
      const int k0 = (t + 1) * BK;
      #pragma unroll
      for (int e = 0; e < NU; ++e) {
        const int idx = tid + 256 * e;
        const int r = idx / BKu;
        const int u = (idx & (BKu - 1)) ^ (SPLIT ? ((r ^ (r >> 2)) & 3) : (r & 7));
        rah[e] = *(const uint4*)(Ah + (size_t)(bm + r) * K + k0 + u * 8);
        rbh[e] = *(const uint4*)(Bh + (size_t)(bn + r) * K + k0 + u * 8);
        if constexpr (SPLIT) {
          ral[e] = *(const uint4*)(Al + (size_t)(bm + r) * K + k0 + u * 8);
          rbl[e] = *(const uint4*)(Bl + (size_t)(bn + r) * K + k0 + u * 8);
        }
      }
    }
    #pragma unroll
    for (int ks = 0; ks < KS; ++ks) {
      bf16x8 fah[4], fbh[4], fal[4], fbl[4];
      #pragma unroll
      for (int i = 0; i < 4; ++i) {
        const int ar = wm * 64 + i * 16 + l15;
        const int br = wn * 64 + i * 16 + l15;
        const int ua = (ks * 4 + g) ^ (SPLIT ? ((ar ^ (ar >> 2)) & 3) : (ar & 7));
        const int ub = (ks * 4 + g) ^ (SPLIT ? ((br ^ (br >> 2)) & 3) : (br & 7));
        fah[i] = *(const bf16x8*)((const char*)&As[buf][0][0] + ar * (BK * 2) + ua * 16);
        fbh[i] = *(const bf16x8*)((const char*)&Bs[buf][0][0] + br * (BK * 2) + ub * 16);
        if constexpr (SPLIT) {
          fal[i] = *(const bf16x8*)((const char*)&As[buf][1][0] + ar * (BK * 2) + ua * 16);
          fbl[i] = *(const bf16x8*)((const char*)&Bs[buf][1][0] + br * (BK * 2) + ub * 16);
        }
      }
      #pragma unroll
      for (int i = 0; i < 4; ++i)
        #pragma unroll
        for (int j = 0; j < 4; ++j) {
          acc[i][j] = __builtin_amdgcn_mfma_f32_16x16x32_bf16(fah[i], fbh[j], acc[i][j], 0, 0, 0);
          if constexpr (SPLIT) {
            acc[i][j] = __builtin_amdgcn_mfma_f32_16x16x32_bf16(fah[i], fbl[j], acc[i][j], 0, 0, 0);
            acc[i][j] = __builtin_amdgcn_mfma_f32_16x16x32_bf16(fal[i], fbh[j], acc[i][j], 0, 0, 0);
          }
        }
      if (ks == 0 && hn) {   // write prefetched tile to the other buffer
        #pragma unroll
        for (int e = 0; e < NU; ++e) {
          const int idx = tid + 256 * e;
          *(uint4*)((char*)&As[buf ^ 1][0][0] + idx * 16) = rah[e];
          *(uint4*)((char*)&Bs[buf ^ 1][0][0] + idx * 16) = rbh[e];
          if constexpr (SPLIT) {
            *(uint4*)((char*)&As[buf ^ 1][1][0] + idx * 16) = ral[e];
            *(uint4*)((char*)&Bs[buf ^ 1][1][0] + idx * 16) = rbl[e];
          }
        }
      }
    }
    __syncthreads();
  }

  // epilogue: D col = lane&15 (n), row = 4g + r (m)
  #pragma unroll
  for (int i = 0; i < 4; ++i) {
    const int m = bm + wm * 64 + i * 16 + 4 * g;
    #pragma unroll
    for (int j = 0; j < 4; ++j) {
      const int n = bn + wn * 64 + j * 16 + l15;
      #pragma unroll
      for (int r = 0; r < 4; ++r) {
        const float v = acc[i][j][r];
        if constexpr (F32OUT)
          ((float*)Cout)[(size_t)(m + r) * N + n] = v;
        else
          ((unsigned short*)Cout)[(size_t)(m + r) * N + n] =
              (unsigned short)(pk_bf16(v, v) & 0xffffu);
      }
    }
  }
}

// ---------------------------------------------------------------------------
// f32 -> bf16 cast
// ---------------------------------------------------------------------------
__global__ __launch_bounds__(256)
void cast_f32_bf16(const float* __restrict__ src, unsigned short* __restrict__ dst,
                   int n4)
{
  const int idx = blockIdx.x * 256 + threadIdx.x;
  for (int i = idx; i < n4; i += gridDim.x * 256) {
    const float4 v = *(const float4*)(src + (size_t)i * 4);
    uint2 o;
    o.x = pk_bf16(v.x, v.y);
    o.y = pk_bf16(v.z, v.w);
    *(uint2*)(dst + (size_t)i * 4) = o;
  }
}

// ---------------------------------------------------------------------------
// f32 -> Dekker split (hi = rne_bf16(x), lo = rne_bf16(x - hi))
// ---------------------------------------------------------------------------
__global__ __launch_bounds__(256)
void split_cast(const float* __restrict__ src, unsigned short* __restrict__ hi,
                unsigned short* __restrict__ lo, int n4)
{
  const int idx = blockIdx.x * 256 + threadIdx.x;
  for (int i = idx; i < n4; i += gridDim.x * 256) {
    const float4 v = *(const float4*)(src + (size_t)i * 4);
    const unsigned int h0 = pk_bf16(v.x, v.y);
    const unsigned int h1 = pk_bf16(v.z, v.w);
    const float ax = __uint_as_float((h0 & 0xffffu) << 16);
    const float ay = __uint_as_float(h0 & 0xffff0000u);
    const float az = __uint_as_float((h1 & 0xffffu) << 16);
    const float aw = __uint_as_float(h1 & 0xffff0000u);
    const unsigned int l0 = pk_bf16(v.x - ax, v.y - ay);
    const unsigned int l1 = pk_bf16(v.z - az, v.w - aw);
    uint2 oh = {h0, h1}, ol = {l0, l1};
    *(uint2*)(hi + (size_t)i * 4) = oh;
    *(uint2*)(lo + (size_t)i * 4) = ol;
  }
}

// ---------------------------------------------------------------------------
// transpose + bf16 cast: src (z, R, C) f32 -> dst (z, C, R) bf16
// ---------------------------------------------------------------------------
__global__ __launch_bounds__(256)
void transpose_cast(const float* __restrict__ src, unsigned short* __restrict__ dst,
                    int R, int C)
{
  __shared__ float tile[32][33];
  const int rb = blockIdx.x * 32, cb = blockIdx.y * 32, z = blockIdx.z;
  const float* s = src + (size_t)z * R * C;
  unsigned short* d = dst + (size_t)z * R * C;
  const int r  = threadIdx.x >> 3;
  const int c4 = (threadIdx.x & 7) << 2;
  const float4 v = *(const float4*)(s + (size_t)(rb + r) * C + cb + c4);
  tile[r][c4 + 0] = v.x; tile[r][c4 + 1] = v.y;
  tile[r][c4 + 2] = v.z; tile[r][c4 + 3] = v.w;
  __syncthreads();
  uint2 o;
  o.x = pk_bf16(tile[c4 + 0][r], tile[c4 + 1][r]);
  o.y = pk_bf16(tile[c4 + 2][r], tile[c4 + 3][r]);
  *(uint2*)(d + (size_t)(cb + r) * R + rb + c4) = o;
}

// ---------------------------------------------------------------------------
// MFMA flash attention v2: head-shared K/V staging.
// Block = 512 thr = 8 waves; wave w = head hg*8+w; all waves share one
// 16-query tile. Pair scheduling (tiles i and 127-i) equalizes causal work:
// 256 blocks == 1 per CU.
// __launch_bounds__(512, 1): live state is ~245 VGPRs (acc[32]=128, qb[16]=64,
// rk/rv=32, temps). (512,2) capped at 128 VGPRs -> ~120 regs spilled, 861 MB/
// dispatch of scratch writes (round-6 counters). 1 block/CU is all LDS (128KB)
// allows anyway.
// ---------------------------------------------------------------------------
static __device__ __forceinline__ void stage_load(
    const unsigned short* __restrict__ ckv_b,
    const unsigned short* __restrict__ ckvT_b,
    int b, int s0, int tid, uint4* rk, uint4* rv)
{
  #pragma unroll
  for (int e = 0; e < 4; ++e) {
    const int idx = tid + 512 * e;
    const int row = idx >> 6;
    const int u   = (idx & 63) ^ (row & 7);
    rk[e] = *(const uint4*)(ckv_b + (size_t)(b * Tc + s0 + row) * LKV + u * 8);
    const int lat = idx >> 2;
    const int uv  = (idx & 3) ^ ((lat ^ (lat >> 2)) & 3);
    rv[e] = *(const uint4*)(ckvT_b + (size_t)(b * LKV + lat) * Tc + s0 + uv * 8);
  }
}

__global__ __launch_bounds__(512, 1)
void mla_attn_mfma2(const unsigned short* __restrict__ qfull_b,  // (BT, C)
                    const unsigned short* __restrict__ MkT_b,    // (512, C)
                    const unsigned short* __restrict__ ckv_b,    // (BT, 512)
                    const unsigned short* __restrict__ ckvT_b,   // [b][512][T]
                    const unsigned short* __restrict__ VeffT_b,  // (C, 512)
                    float* __restrict__ y)                       // (BT, C)
{
  __shared__ unsigned short Kl[2][32 * 512];   // 2 x 32 KB
  __shared__ unsigned short Vt[2][512 * 32];   // 2 x 32 KB

  const int tid  = threadIdx.x;
  const int lane = tid & 63;
  const int w    = tid >> 6;
  const int g    = lane >> 4;
  const int l15  = lane & 15;

  // XCD-aware decode: each XCD sticks to one (batch, head-group)
  const int bid   = blockIdx.x;
  const int xcd   = bid & 7;
  const int slot  = bid >> 3;
  const int b     = xcd >> 2;
  const int hg    = (xcd >> 1) & 1;
  const int ipair = (slot << 1) | (xcd & 1);   // 0..63
  const int h     = hg * 8 + w;

  const int srcA = ((2 * (g & 1)) << 4) | l15;
  const int srcB = srcA + 16;
  const bool hiF = (g >> 1);
  const f32x4 zero4 = {0.f, 0.f, 0.f, 0.f};

  for (int half = 0; half < 2; ++half) {
    const int qt = half ? (127 - ipair) : ipair;
    const int q0 = qt << 4;
    const int qg = q0 + l15;

    // ---- issue tile-0 staging loads early (hidden under q_lat prologue) ----
    uint4 rk[4], rv[4];
    stage_load(ckv_b, ckvT_b, b, 0, tid, rk, rv);

    // ---- prologue: q_lat^T = MkT . qfull^T (per-head) ----
    f32x4 acc[32];
    #pragma unroll
    for (int i = 0; i < 32; ++i) acc[i] = zero4;
    #pragma unroll
    for (int ks4 = 0; ks4 < 4; ++ks4) {
      const bf16x8 bq = *(const bf16x8*)(qfull_b + (size_t)(b * Tc + q0 + l15) * Cc
                                         + h * HSc + ks4 * 32 + g * 8);
      #pragma unroll
      for (int lf = 0; lf < 32; ++lf) {
        const bf16x8 aq = *(const bf16x8*)(MkT_b + (size_t)(16 * lf + l15) * Cc
                                           + h * HSc + ks4 * 32 + g * 8);
        acc[lf] = __builtin_amdgcn_mfma_f32_16x16x32_bf16(aq, bq, acc[lf], 0, 0, 0);
      }
    }
    const float scale = 0.08838834764831845f;  // 1/sqrt(128)
    #pragma unroll
    for (int i = 0; i < 32; ++i) {
      acc[i][0] *= scale; acc[i][1] *= scale; acc[i][2] *= scale; acc[i][3] *= scale;
    }

    // ---- pack Q into B-fragments ----
    bf16x8 qb[16];
    #pragma unroll
    for (int ks = 0; ks < 16; ++ks) {
      const unsigned int w00 = pk_bf16(acc[2 * ks][0], acc[2 * ks][1]);
      const unsigned int w01 = pk_bf16(acc[2 * ks][2], acc[2 * ks][3]);
      const unsigned int w10 = pk_bf16(acc[2 * ks + 1][0], acc[2 * ks + 1][1]);
      const unsigned int w11 = pk_bf16(acc[2 * ks + 1][2], acc[2 * ks + 1][3]);
      qb[ks] = pack_frag(w00, w01, w10, w11, srcA, srcB, hiF);
    }
    #pragma unroll
    for (int i = 0; i < 32; ++i) acc[i] = zero4;   // acc becomes ctx^T

    // ---- write tile 0 to buffer 0 ----
    #pragma unroll
    for (int e = 0; e < 4; ++e) {
      const int idx = tid + 512 * e;
      *(uint4*)((char*)&Kl[0][0] + idx * 16) = rk[e];
      *(uint4*)((char*)&Vt[0][0] + idx * 16) = rv[e];
    }
    float m_i = -__builtin_inff();
    float l_i = 0.f;
    __syncthreads();

    const int ntiles = ((q0 + 15) >> 5) + 1;
    for (int st = 0; st < ntiles; ++st) {
      const int cur = st & 1;
      const int s0  = st * 32;
      const bool hasNext = (st + 1 < ntiles);
      if (hasNext) stage_load(ckv_b, ckvT_b, b, s0 + 32, tid, rk, rv);

      // --- QK: S^T strips ---
      f32x4 s0f = zero4, s1f = zero4;
      #pragma unroll
      for (int ks = 0; ks < 16; ++ks) {
        const int off = ((ks * 4 + g) ^ (l15 & 7)) * 16;
        const bf16x8 a0 = *(const bf16x8*)((const char*)&Kl[cur][0] + l15 * 1024 + off);
        const bf16x8 a1 = *(const bf16x8*)((const char*)&Kl[cur][0] + (16 + l15) * 1024 + off);
        s0f = __builtin_amdgcn_mfma_f32_16x16x32_bf16(a0, qb[ks], s0f, 0, 0, 0);
        s1f = __builtin_amdgcn_mfma_f32_16x16x32_bf16(a1, qb[ks], s1f, 0, 0, 0);
      }

      // --- mask + online softmax (per-lane stats; q = col = lane&15) ---
      float sv[8];
      #pragma unroll
      for (int r = 0; r < 4; ++r) { sv[r] = s0f[r]; sv[4 + r] = s1f[r]; }
      if (st == ntiles - 1) {
        #pragma unroll
        for (int kf = 0; kf < 2; ++kf)
          #pragma unroll
          for (int r = 0; r < 4; ++r) {
            const int key = s0 + 16 * kf + 4 * g + r;
            if (key > qg) sv[4 * kf + r] = -__builtin_inff();
          }
      }
      float vmax = sv[0];
      #pragma unroll
      for (int i = 1; i < 8; ++i) vmax = fmaxf(vmax, sv[i]);
      vmax = fmaxf(vmax, __shfl_xor(vmax, 16));
      vmax = fmaxf(vmax, __shfl_xor(vmax, 32));

      if (!__all(vmax <= m_i + 8.0f)) {   // defer-max
        const float m_new = fmaxf(m_i, vmax);
        const float scl = __expf(m_i - m_new);
        l_i *= scl;
        #pragma unroll
        for (int i = 0; i < 32; ++i) {
          acc[i][0] *= scl; acc[i][1] *= scl; acc[i][2] *= scl; acc[i][3] *= scl;
        }
        m_i = m_new;
      }

      float p[8];
      float lsum = 0.f;
      #pragma unroll
      for (int i = 0; i < 8; ++i) { p[i] = __expf(sv[i] - m_i); lsum += p[i]; }
      lsum += __shfl_xor(lsum, 16);
      lsum += __shfl_xor(lsum, 32);
      l_i += lsum;

      // --- write prefetched tile into the idle buffer (T14 async-split) ---
      if (hasNext) {
        #pragma unroll
        for (int e = 0; e < 4; ++e) {
          const int idx = tid + 512 * e;
          *(uint4*)((char*)&Kl[cur ^ 1][0] + idx * 16) = rk[e];
          *(uint4*)((char*)&Vt[cur ^ 1][0] + idx * 16) = rv[e];
        }
      }

      // --- build P^T B-fragment ---
      const unsigned int W00 = pk_bf16(p[0], p[1]);
      const unsigned int W01 = pk_bf16(p[2], p[3]);
      const unsigned int W10 = pk_bf16(p[4], p[5]);
      const unsigned int W11 = pk_bf16(p[6], p[7]);
      const bf16x8 pfr = pack_frag(W00, W01, W10, W11, srcA, srcB, hiF);

      // --- PV: ctx^T += V^T . P^T ---
      #pragma unroll
      for (int lf = 0; lf < 32; ++lf) {
        const int lat = 16 * lf + l15;
        const bf16x8 av = *(const bf16x8*)((const char*)&Vt[cur][0] + lat * 64
                                           + ((g ^ ((lat ^ (lat >> 2)) & 3)) * 16));
        acc[lf] = __builtin_amdgcn_mfma_f32_16x16x32_bf16(av, pfr, acc[lf], 0, 0, 0);
      }
      __syncthreads();
    }

    // ---- epilogue: y^T = v_eff^T . (ctx^T / l) ----
    const float inv_l = 1.0f / l_i;
    f32x4 yacc[8];
    #pragma unroll
    for (int i = 0; i < 8; ++i) yacc[i] = zero4;
    #pragma unroll
    for (int ks = 0; ks < 16; ++ks) {
      const unsigned int w00 = pk_bf16(acc[2 * ks][0] * inv_l, acc[2 * ks][1] * inv_l);
      const unsigned int w01 = pk_bf16(acc[2 * ks][2] * inv_l, acc[2 * ks][3] * inv_l);
      const unsigned int w10 = pk_bf16(acc[2 * ks + 1][0] * inv_l, acc[2 * ks + 1][1] * inv_l);
      const unsigned int w11 = pk_bf16(acc[2 * ks + 1][2] * inv_l, acc[2 * ks + 1][3] * inv_l);
      const bf16x8 cf = pack_frag(w00, w01, w10, w11, srcA, srcB, hiF);
      #pragma unroll
      for (int hf = 0; hf < 8; ++hf) {
        const bf16x8 aV = *(const bf16x8*)(VeffT_b + (size_t)(h * HSc + 16 * hf + l15) * LKV
                                           + ks * 32 + g * 8);
        yacc[hf] = __builtin_amdgcn_mfma_f32_16x16x32_bf16(aV, cf, yacc[hf], 0, 0, 0);
      }
    }
    float* yp = y + (size_t)(b * Tc + qg) * Cc + h * HSc;
    #pragma unroll
    for (int hf = 0; hf < 8; ++hf) {
      float4 v = {yacc[hf][0], yacc[hf][1], yacc[hf][2], yacc[hf][3]};
      *(float4*)(yp + 16 * hf + 4 * g) = v;
    }
  }
}

// ---------------------------------------------------------------------------
extern "C" void kernel_launch(void* const* d_in, const int* in_sizes, int n_in,
                              void* d_out, int out_size, void* d_ws, size_t ws_size,
                              hipStream_t stream)
{
  (void)in_sizes; (void)n_in; (void)out_size;

  const float* x    = (const float*)d_in[0];
  const float* Wdq  = (const float*)d_in[1];   // (LQ, C)
  const float* Wuq  = (const float*)d_in[2];   // (C, LQ)
  const float* Wdkv = (const float*)d_in[3];   // (LKV, C)
  const float* Wuk  = (const float*)d_in[4];   // (C, LKV)
  const float* Wuv  = (const float*)d_in[5];   // (C, LKV)
  const float* Wo   = (const float*)d_in[6];   // (C, C)

  float* y_out = (float*)d_out;                         // (BT, C)
  float* ckv   = (float*)d_out + (size_t)BT * Cc;       // (BT, LKV) fp32 output

  constexpr size_t MB = 1ull << 20;
  char* ws = (char*)d_ws;
  if (ws_size < 48 * MB) return;  // loud failure if workspace too small

  // phase-1 layout
  unsigned short* xh    = (unsigned short*)(ws + 0 * MB);    // 16MB
  unsigned short* xl    = (unsigned short*)(ws + 16 * MB);   // 16MB
  unsigned short* Wdqh  = (unsigned short*)(ws + 32 * MB);   // 2MB
  unsigned short* Wdql  = (unsigned short*)(ws + 34 * MB);   // 2MB
  float*          t1f   = (float*)         (ws + 36 * MB);   // 8MB
  unsigned short* Wdkvh = (unsigned short*)(ws + 44 * MB);   // 2MB
  unsigned short* Wdkvl = (unsigned short*)(ws + 46 * MB);   // 2MB  (peak 48MB)
  // phase-2 layout (reuses freed regions)
  unsigned short* t1h     = (unsigned short*)(ws + 0 * MB);  // 4MB
  unsigned short* t1l     = (unsigned short*)(ws + 4 * MB);  // 4MB
  unsigned short* Wuqh    = (unsigned short*)(ws + 8 * MB);  // 2MB
  unsigned short* Wuql    = (unsigned short*)(ws + 10 * MB); // 2MB
  unsigned short* qfull_b = (unsigned short*)(ws + 12 * MB); // 16MB -> 28
  unsigned short* ckvT_b  = (unsigned short*)(ws + 28 * MB); // 4MB  -> 32
  unsigned short* ckv_b   = (unsigned short*)(ws + 32 * MB); // 4MB  -> 36
  unsigned short* MkT_b   = (unsigned short*)(ws + 36 * MB); // 2MB  -> 38
  float*          A1      = (float*)         (ws + 44 * MB); // 1MB
  unsigned short* Wo_b    = (unsigned short*)(ws + 0 * MB);  // 8MB (after t1 dead)
  unsigned short* WuvT_b  = (unsigned short*)(ws + 8 * MB);  // 2MB (after Wuq dead)
  unsigned short* VeffT_b = (unsigned short*)(ws + 10 * MB); // 2MB

  const dim3 blk(256);

  // q/kv projection path (Dekker split -> fp32-grade MFMA)
  split_cast<<<2048, blk, 0, stream>>>(x, xh, xl, BT * Cc / 4);
  split_cast<<<512, blk, 0, stream>>>(Wdq, Wdqh, Wdql, LQ * Cc / 4);
  gemm_bt_bf16<1, 1><<<dim3(LQ / 128, BT / 128), blk, 0, stream>>>(
      xh, xl, Wdqh, Wdql, t1f, BT, LQ, Cc);
  split_cast<<<512, blk, 0, stream>>>(Wdkv, Wdkvh, Wdkvl, LKV * Cc / 4);
  gemm_bt_bf16<1, 1><<<dim3(LKV / 128, BT / 128), blk, 0, stream>>>(
      xh, xl, Wdkvh, Wdkvl, ckv, BT, LKV, Cc);                 // ckv output
  split_cast<<<512, blk, 0, stream>>>(t1f, t1h, t1l, BT * LQ / 4);
  split_cast<<<512, blk, 0, stream>>>(Wuq, Wuqh, Wuql, Cc * LQ / 4);
  gemm_bt_bf16<1, 0><<<dim3(Cc / 128, BT / 128), blk, 0, stream>>>(
      t1h, t1l, Wuqh, Wuql, qfull_b, BT, Cc, LQ);
  // v_eff^T = Wo @ Wuv (plain bf16 MFMA)
  cast_f32_bf16<<<1024, blk, 0, stream>>>(Wo, Wo_b, Cc * Cc / 4);
  transpose_cast<<<dim3(Cc / 32, LKV / 32, 1), blk, 0, stream>>>(Wuv, WuvT_b, Cc, LKV);
  gemm_bt_bf16<0, 0><<<dim3(LKV / 128, Cc / 128), blk, 0, stream>>>(
      Wo_b, nullptr, WuvT_b, nullptr, VeffT_b, Cc, LKV, Cc);
  // k_eff^T (small, fp32 vector path, identical to validated round 2)
  gemm_nt<0><<<dim3(LKV / 64, LQ / 64), blk, 0, stream>>>(
      Wuq, Wuk, A1, LQ, LKV, Cc, 1, LQ, 1, LKV);
  gemm_nt<1><<<dim3(Cc / 64, LKV / 64), blk, 0, stream>>>(
      A1, Wdq, MkT_b, LKV, Cc, LQ, 1, LKV, 1, Cc);
  // bf16 copies of ckv
  cast_f32_bf16<<<1024, blk, 0, stream>>>(ckv, ckv_b, BT * LKV / 4);
  transpose_cast<<<dim3(Tc / 32, LKV / 32, Bc), blk, 0, stream>>>(ckv, ckvT_b, Tc, LKV);
  // flash attention + absorbed output projection
  mla_attn_mfma2<<<dim3(256), dim3(512), 0, stream>>>(
      qfull_b, MkT_b, ckv_b, ckvT_b, VeffT_b, y_out);
}